// Round 2
// baseline (2319.714 us; speedup 1.0000x reference)
//
#include <hip/hip_runtime.h>
#include <math.h>

#define MASKN 1023

typedef unsigned short ushort_t;

__device__ __forceinline__ float gelu_f(float x) {
    return 0.5f * x * (1.0f + erff(x * 0.7071067811865475f));
}

// ---- bf16 storage helpers (compute stays fp32) ----
__device__ __forceinline__ float bf2f(ushort_t h) {
    return __uint_as_float(((unsigned int)h) << 16);
}
__device__ __forceinline__ ushort_t f2bf(float f) {
    unsigned int u = __float_as_uint(f);
    u += 0x7FFFu + ((u >> 16) & 1u);   // round to nearest even
    return (ushort_t)(u >> 16);
}
struct us4 { ushort_t x, y, z, w; };

__device__ __forceinline__ float ld1(const float* p) { return *p; }
__device__ __forceinline__ float ld1(const ushort_t* p) { return bf2f(*p); }
__device__ __forceinline__ float4 ld4(const float* p) { return *(const float4*)p; }
__device__ __forceinline__ float4 ld4(const ushort_t* p) {
    us4 v = *(const us4*)p;
    return make_float4(bf2f(v.x), bf2f(v.y), bf2f(v.z), bf2f(v.w));
}
__device__ __forceinline__ void st4(float* p, float4 v) { *(float4*)p = v; }
__device__ __forceinline__ void st4(ushort_t* p, float4 v) {
    us4 h; h.x = f2bf(v.x); h.y = f2bf(v.y); h.z = f2bf(v.z); h.w = f2bf(v.w);
    *(us4*)p = h;
}

// ---------------- twiddle table: ct[j]=cos(2pi j/1024), st[j]=sin(2pi j/1024)
__global__ void k_fill_tw(float* __restrict__ ct, float* __restrict__ st) {
    int j = blockIdx.x * 256 + threadIdx.x;   // 0..1023
    float ang = (float)j * (6.283185307179586f / 1024.0f);
    float s, c;
    sincosf(ang, &s, &c);
    ct[j] = c; st[j] = s;
}

// ---------------- shallow: vt[p][c] = gelu(in[p][0]*Wsh[0][c] + in[p][1]*Wsh[1][c] + bsh[c])
template<typename T>
__global__ __launch_bounds__(256) void k_shallow(const float* __restrict__ in,
        const float* __restrict__ Wsh, const float* __restrict__ bsh,
        T* __restrict__ vt) {
    int tid = blockIdx.x * 256 + threadIdx.x;
    int p = tid >> 4, c0 = (tid & 15) << 2;
    float a0 = in[p * 2], a1 = in[p * 2 + 1];
    float4 w0 = *(const float4*)&Wsh[c0];
    float4 w1 = *(const float4*)&Wsh[64 + c0];
    float4 b  = *(const float4*)&bsh[c0];
    float4 r;
    r.x = gelu_f(fmaf(a0, w0.x, fmaf(a1, w1.x, b.x)));
    r.y = gelu_f(fmaf(a0, w0.y, fmaf(a1, w1.y, b.y)));
    r.z = gelu_f(fmaf(a0, w0.z, fmaf(a1, w1.z, b.z)));
    r.w = gelu_f(fmaf(a0, w0.w, fmaf(a1, w1.w, b.w)));
    st4(&vt[(size_t)p * 64 + c0], r);
}

// ---------------- F1: g[x,k2,c] = sum_y vt[x,y,c] * e^{-2pi i k2 y/1024}
template<typename T>
__global__ __launch_bounds__(256) void k_f1(const T* __restrict__ vt,
        const float* __restrict__ ctg, const float* __restrict__ stg,
        float* __restrict__ gr, float* __restrict__ gi) {
    __shared__ float ct[1024], st[1024];
    __shared__ __align__(16) float vbuf[8192];
    int t = threadIdx.x;
    int x = blockIdx.x;
    #pragma unroll
    for (int i = 0; i < 4; ++i) { int j = t + 256 * i; ct[j] = ctg[j]; st[j] = stg[j]; }
    int half = t >> 7;
    int tl = t & 127;
    int c0 = (tl & 15) << 2;
    int k0 = (tl >> 4) << 2;
    float accr[4][4], acci[4][4];
    #pragma unroll
    for (int j = 0; j < 4; ++j)
        #pragma unroll
        for (int i = 0; i < 4; ++i) { accr[j][i] = 0.f; acci[j][i] = 0.f; }
    int idxs[4];
    #pragma unroll
    for (int j = 0; j < 4; ++j) idxs[j] = ((k0 + j) * (half << 9)) & MASKN;
    const T* vrow = vt + (size_t)x * 65536;
    for (int ch = 0; ch < 8; ++ch) {
        __syncthreads();
        #pragma unroll
        for (int i = 0; i < 32; ++i) {
            int o = t + 256 * i;
            int h = o >> 12, oo = o & 4095;
            vbuf[o] = ld1(vrow + h * 32768 + ch * 4096 + oo);
        }
        __syncthreads();
        const float* vb = &vbuf[(half << 12) + c0];
        #pragma unroll 4
        for (int yl = 0; yl < 64; ++yl) {
            float4 v = *(const float4*)(vb + (yl << 6));
            #pragma unroll
            for (int j = 0; j < 4; ++j) {
                float cj = ct[idxs[j]], sj = st[idxs[j]];
                idxs[j] = (idxs[j] + k0 + j) & MASKN;
                accr[j][0] = fmaf(v.x, cj, accr[j][0]);
                accr[j][1] = fmaf(v.y, cj, accr[j][1]);
                accr[j][2] = fmaf(v.z, cj, accr[j][2]);
                accr[j][3] = fmaf(v.w, cj, accr[j][3]);
                acci[j][0] = fmaf(v.x, -sj, acci[j][0]);
                acci[j][1] = fmaf(v.y, -sj, acci[j][1]);
                acci[j][2] = fmaf(v.z, -sj, acci[j][2]);
                acci[j][3] = fmaf(v.w, -sj, acci[j][3]);
            }
        }
    }
    __syncthreads();
    if (half == 0) {
        float* rb = &vbuf[tl * 32];
        #pragma unroll
        for (int j = 0; j < 4; ++j)
            #pragma unroll
            for (int i = 0; i < 4; ++i) { rb[j * 4 + i] = accr[j][i]; rb[16 + j * 4 + i] = acci[j][i]; }
    }
    __syncthreads();
    if (half == 1) {
        const float* rb = &vbuf[tl * 32];
        #pragma unroll
        for (int j = 0; j < 4; ++j) {
            float4 rr, ii;
            rr.x = accr[j][0] + rb[j * 4 + 0]; rr.y = accr[j][1] + rb[j * 4 + 1];
            rr.z = accr[j][2] + rb[j * 4 + 2]; rr.w = accr[j][3] + rb[j * 4 + 3];
            ii.x = acci[j][0] + rb[16 + j * 4 + 0]; ii.y = acci[j][1] + rb[16 + j * 4 + 1];
            ii.z = acci[j][2] + rb[16 + j * 4 + 2]; ii.w = acci[j][3] + rb[16 + j * 4 + 3];
            *(float4*)&gr[(size_t)x * 2048 + (k0 + j) * 64 + c0] = rr;
            *(float4*)&gi[(size_t)x * 2048 + (k0 + j) * 64 + c0] = ii;
        }
    }
}

// ---------------- F2: fpart[cx,k1,k2,c] = sum_{x in chunk cx} g[x,k2,c] * e^{-2pi i k1 x/1024}
__global__ __launch_bounds__(256) void k_f2(const float* __restrict__ gr, const float* __restrict__ gi,
        const float* __restrict__ ctg, const float* __restrict__ stg,
        float* __restrict__ fpr, float* __restrict__ fpi) {
    __shared__ float ct[1024], st[1024];
    int t = threadIdx.x;
    #pragma unroll
    for (int i = 0; i < 4; ++i) { int j = t + 256 * i; ct[j] = ctg[j]; st[j] = stg[j]; }
    __syncthreads();
    int cx = blockIdx.x;          // 0..7
    int k2 = blockIdx.y;          // 0..31
    int c = t & 63;
    int k10 = (t >> 6) * 8;
    float fr[8], fi[8];
    int idxs[8];
    #pragma unroll
    for (int j = 0; j < 8; ++j) { fr[j] = 0.f; fi[j] = 0.f; idxs[j] = ((k10 + j) * (cx * 128)) & MASKN; }
    for (int x = cx * 128; x < cx * 128 + 128; ++x) {
        float r = gr[(size_t)x * 2048 + k2 * 64 + c];
        float m = gi[(size_t)x * 2048 + k2 * 64 + c];
        #pragma unroll
        for (int j = 0; j < 8; ++j) {
            float cj = ct[idxs[j]], sj = st[idxs[j]];
            idxs[j] = (idxs[j] + k10 + j) & MASKN;
            fr[j] = fmaf(r, cj, fmaf(m, sj, fr[j]));
            fi[j] = fmaf(m, cj, fmaf(-r, sj, fi[j]));
        }
    }
    #pragma unroll
    for (int j = 0; j < 8; ++j) {
        fpr[(size_t)cx * 65536 + (k10 + j) * 2048 + k2 * 64 + c] = fr[j];
        fpi[(size_t)cx * 65536 + (k10 + j) * 2048 + k2 * 64 + c] = fi[j];
    }
}

// ---------------- MIX: Rf[m,d] = sum_c f[m,c] * (Rr+iRi)[m,c,d], f = sum of 8 partials
__global__ __launch_bounds__(64) void k_mix(const float* __restrict__ fpr, const float* __restrict__ fpi,
        const float* __restrict__ Rr, const float* __restrict__ Ri,
        float* __restrict__ Rfr, float* __restrict__ Rfi) {
    __shared__ float fr[64], fi[64];
    int m = blockIdx.x;
    int d = threadIdx.x;
    float sr = 0.f, si = 0.f;
    #pragma unroll
    for (int ch = 0; ch < 8; ++ch) {
        sr += fpr[(size_t)ch * 65536 + m * 64 + d];
        si += fpi[(size_t)ch * 65536 + m * 64 + d];
    }
    fr[d] = sr; fi[d] = si;
    __syncthreads();
    const float* Rrb = Rr + (size_t)m * 4096;
    const float* Rib = Ri + (size_t)m * 4096;
    float ar = 0.f, ai = 0.f;
    for (int c = 0; c < 64; ++c) {
        float rr = Rrb[c * 64 + d], ri = Rib[c * 64 + d];
        ar = fmaf(fr[c], rr, fmaf(-fi[c], ri, ar));
        ai = fmaf(fr[c], ri, fmaf(fi[c], rr, ai));
    }
    Rfr[m * 64 + d] = ar;
    Rfi[m * 64 + d] = ai;
}

// ---------------- I1: B[n1,k2,d] = w_k2/2^20 * sum_k1 Rf[k1,k2,d] * e^{+2pi i k1 n1/1024}
__global__ __launch_bounds__(256) void k_i1(const float* __restrict__ Rfr, const float* __restrict__ Rfi,
        const float* __restrict__ ctg, const float* __restrict__ stg,
        float* __restrict__ Br, float* __restrict__ Bi) {
    __shared__ float ct[1024], st[1024];
    int t = threadIdx.x;
    #pragma unroll
    for (int i = 0; i < 4; ++i) { int j = t + 256 * i; ct[j] = ctg[j]; st[j] = stg[j]; }
    __syncthreads();
    int n1 = blockIdx.x;
    int d = t & 63;
    int k20 = (t >> 6) * 8;
    float br[8], bi[8];
    #pragma unroll
    for (int j = 0; j < 8; ++j) { br[j] = 0.f; bi[j] = 0.f; }
    int idx = 0;
    for (int k1 = 0; k1 < 32; ++k1) {
        float cc = ct[idx], ss = st[idx];
        idx = (idx + n1) & MASKN;
        #pragma unroll
        for (int j = 0; j < 8; ++j) {
            float rr = Rfr[(k1 * 32 + k20 + j) * 64 + d];
            float ri = Rfi[(k1 * 32 + k20 + j) * 64 + d];
            br[j] = fmaf(rr, cc, fmaf(-ri, ss, br[j]));
            bi[j] = fmaf(rr, ss, fmaf(ri, cc, bi[j]));
        }
    }
    #pragma unroll
    for (int j = 0; j < 8; ++j) {
        int k2 = k20 + j;
        float sc = (k2 == 0 ? 1.0f : 2.0f) * 9.5367431640625e-7f;   // 1/2^20
        Br[(size_t)n1 * 2048 + k2 * 64 + d] = br[j] * sc;
        Bi[(size_t)n1 * 2048 + k2 * 64 + d] = bi[j] * sc;
    }
}

// ---------------- I2 (fused): vt[n1,n2,d] = gelu( sum_k2 (Br*cos - Bi*sin) + sum_c vt[n1,n2,c]*w[c,d] )
template<typename T>
__global__ __launch_bounds__(256) void k_i2(T* __restrict__ vt,
        const float* __restrict__ Brg, const float* __restrict__ Big,
        const float* __restrict__ w,
        const float* __restrict__ ctg, const float* __restrict__ stg) {
    __shared__ float ct[1024], st[1024];
    __shared__ __align__(16) float vT[64 * 68];
    __shared__ __align__(16) float wS[64 * 68];
    __shared__ __align__(16) float BrS[32 * 68];
    __shared__ __align__(16) float BiS[32 * 68];
    int t = threadIdx.x;
    int chunk = blockIdx.x;   // 0..15
    int n1 = blockIdx.y;
    #pragma unroll
    for (int i = 0; i < 4; ++i) { int j = t + 256 * i; ct[j] = ctg[j]; st[j] = stg[j]; }
    #pragma unroll
    for (int i = 0; i < 16; ++i) { int o = t + 256 * i; wS[(o >> 6) * 68 + (o & 63)] = w[o]; }
    #pragma unroll
    for (int i = 0; i < 8; ++i) {
        int o = t + 256 * i;
        BrS[(o >> 6) * 68 + (o & 63)] = Brg[(size_t)n1 * 2048 + o];
        BiS[(o >> 6) * 68 + (o & 63)] = Big[(size_t)n1 * 2048 + o];
    }
    T* vrow = vt + (size_t)n1 * 65536 + chunk * 4096;
    #pragma unroll
    for (int i = 0; i < 16; ++i) { int o = t + 256 * i; vT[(o & 63) * 68 + (o >> 6)] = ld1(&vrow[o]); }
    __syncthreads();
    int d0 = (t & 15) << 2;
    int n20 = (t >> 4) << 2;
    int n2g0 = chunk * 64 + n20;
    float acc[4][4];
    #pragma unroll
    for (int i = 0; i < 4; ++i)
        #pragma unroll
        for (int j = 0; j < 4; ++j) acc[i][j] = 0.f;
    // skip connection: x @ w
    #pragma unroll 8
    for (int c = 0; c < 64; ++c) {
        float4 va = *(const float4*)&vT[c * 68 + n20];
        float4 wb = *(const float4*)&wS[c * 68 + d0];
        acc[0][0] = fmaf(va.x, wb.x, acc[0][0]); acc[0][1] = fmaf(va.x, wb.y, acc[0][1]);
        acc[0][2] = fmaf(va.x, wb.z, acc[0][2]); acc[0][3] = fmaf(va.x, wb.w, acc[0][3]);
        acc[1][0] = fmaf(va.y, wb.x, acc[1][0]); acc[1][1] = fmaf(va.y, wb.y, acc[1][1]);
        acc[1][2] = fmaf(va.y, wb.z, acc[1][2]); acc[1][3] = fmaf(va.y, wb.w, acc[1][3]);
        acc[2][0] = fmaf(va.z, wb.x, acc[2][0]); acc[2][1] = fmaf(va.z, wb.y, acc[2][1]);
        acc[2][2] = fmaf(va.z, wb.z, acc[2][2]); acc[2][3] = fmaf(va.z, wb.w, acc[2][3]);
        acc[3][0] = fmaf(va.w, wb.x, acc[3][0]); acc[3][1] = fmaf(va.w, wb.y, acc[3][1]);
        acc[3][2] = fmaf(va.w, wb.z, acc[3][2]); acc[3][3] = fmaf(va.w, wb.w, acc[3][3]);
    }
    // inverse k2 -> n2
    int idxs[4] = {0, 0, 0, 0};
    #pragma unroll 4
    for (int k2 = 0; k2 < 32; ++k2) {
        float4 br = *(const float4*)&BrS[k2 * 68 + d0];
        float4 bi = *(const float4*)&BiS[k2 * 68 + d0];
        #pragma unroll
        for (int i = 0; i < 4; ++i) {
            float ci = ct[idxs[i]], si = st[idxs[i]];
            idxs[i] = (idxs[i] + n2g0 + i) & MASKN;
            acc[i][0] = fmaf(ci, br.x, fmaf(-si, bi.x, acc[i][0]));
            acc[i][1] = fmaf(ci, br.y, fmaf(-si, bi.y, acc[i][1]));
            acc[i][2] = fmaf(ci, br.z, fmaf(-si, bi.z, acc[i][2]));
            acc[i][3] = fmaf(ci, br.w, fmaf(-si, bi.w, acc[i][3]));
        }
    }
    #pragma unroll
    for (int i = 0; i < 4; ++i) {
        float4 r;
        r.x = gelu_f(acc[i][0]); r.y = gelu_f(acc[i][1]);
        r.z = gelu_f(acc[i][2]); r.w = gelu_f(acc[i][3]);
        st4(&vrow[(n20 + i) * 64 + d0], r);
    }
}

// ---------------- projection: out[p] = sum_c vt[p,c]*Wp[c] + bp[0]
template<typename T>
__global__ __launch_bounds__(256) void k_proj(const T* __restrict__ vt,
        const float* __restrict__ Wp, const float* __restrict__ bp,
        float* __restrict__ out) {
    __shared__ float wp[64];
    int t = threadIdx.x;
    if (t < 64) wp[t] = Wp[t];
    __syncthreads();
    int p = blockIdx.x * 256 + t;
    const T* v = vt + (size_t)p * 64;
    float acc = bp[0];
    #pragma unroll
    for (int i = 0; i < 16; ++i) {
        float4 a = ld4(&v[i * 4]);
        acc = fmaf(a.x, wp[i * 4 + 0], acc);
        acc = fmaf(a.y, wp[i * 4 + 1], acc);
        acc = fmaf(a.z, wp[i * 4 + 2], acc);
        acc = fmaf(a.w, wp[i * 4 + 3], acc);
    }
    out[p] = acc;
}

template<typename T>
static void run_pipeline(void* const* d_in, T* vt, float* small, float* out, hipStream_t stream) {
    const float* in  = (const float*)d_in[0];
    const float* Wsh = (const float*)d_in[1];
    const float* bsh = (const float*)d_in[2];
    const float* Wp  = (const float*)d_in[15];
    const float* bp  = (const float*)d_in[16];
    // small-buffer layout (floats): 2048 tables + 2*2097152 g + 2*524288 fp + 2*65536 Rf
    float* ctab = small;                 // 1024
    float* stab = ctab + 1024;           // 1024
    float* grg  = stab + 1024;           // 2097152
    float* gig  = grg + 2097152;         // 2097152
    float* fpr  = gig + 2097152;         // 524288
    float* fpi  = fpr + 524288;          // 524288
    float* Rfr  = fpi + 524288;          // 65536
    float* Rfi  = Rfr + 65536;           // 65536
    float* Brg  = grg;                   // alias g (dead after F2)
    float* Big  = gig;

    k_fill_tw<<<4, 256, 0, stream>>>(ctab, stab);
    k_shallow<T><<<65536, 256, 0, stream>>>(in, Wsh, bsh, vt);
    for (int L = 0; L < 4; ++L) {
        const float* Rr = (const float*)d_in[3 + L * 3];
        const float* Ri = (const float*)d_in[4 + L * 3];
        const float* w  = (const float*)d_in[5 + L * 3];
        k_f1<T><<<1024, 256, 0, stream>>>(vt, ctab, stab, grg, gig);
        k_f2<<<dim3(8, 32), 256, 0, stream>>>(grg, gig, ctab, stab, fpr, fpi);
        k_mix<<<1024, 64, 0, stream>>>(fpr, fpi, Rr, Ri, Rfr, Rfi);
        k_i1<<<1024, 256, 0, stream>>>(Rfr, Rfi, ctab, stab, Brg, Big);
        k_i2<T><<<dim3(16, 1024), 256, 0, stream>>>(vt, Brg, Big, w, ctab, stab);
    }
    k_proj<T><<<4096, 256, 0, stream>>>(vt, Wp, bp, out);
}

extern "C" void kernel_launch(void* const* d_in, const int* in_sizes, int n_in,
                              void* d_out, int out_size, void* d_ws, size_t ws_size,
                              hipStream_t stream) {
    const size_t VT_ELEMS = 67108864ull;                    // 1024*1024*64
    const size_t SMALL_FLOATS = 2048ull + 2ull * 2097152ull + 2ull * 524288ull + 2ull * 65536ull;
    const size_t FP32_NEED = (VT_ELEMS + SMALL_FLOATS) * 4ull;      // ~290 MB
    float* out = (float*)d_out;

    if (ws_size >= FP32_NEED) {
        // Plan A: fp32 activations
        float* vt = (float*)d_ws;
        float* small = vt + VT_ELEMS;
        run_pipeline<float>(d_in, vt, small, out, stream);
    } else {
        // Plan B: bf16 activation storage (128 MB), fp32 everything else (~21 MB)
        ushort_t* vt = (ushort_t*)d_ws;
        float* small = (float*)((char*)d_ws + VT_ELEMS * sizeof(ushort_t));
        run_pipeline<ushort_t>(d_in, vt, small, out, stream);
    }
}

// Round 3
// 1880.660 us; speedup vs baseline: 1.2335x; 1.2335x over previous
//
#include <hip/hip_runtime.h>
#include <math.h>

#define MASKN 1023

typedef unsigned short ushort_t;
typedef __attribute__((ext_vector_type(8))) short short8;
typedef __attribute__((ext_vector_type(4))) float floatx4;

__device__ __forceinline__ float gelu_f(float x) {
    return 0.5f * x * (1.0f + erff(x * 0.7071067811865475f));
}

// ---- bf16 storage helpers (compute stays fp32) ----
__device__ __forceinline__ float bf2f(ushort_t h) {
    return __uint_as_float(((unsigned int)h) << 16);
}
__device__ __forceinline__ ushort_t f2bf(float f) {
    unsigned int u = __float_as_uint(f);
    u += 0x7FFFu + ((u >> 16) & 1u);   // round to nearest even
    return (ushort_t)(u >> 16);
}
struct us4 { ushort_t x, y, z, w; };

__device__ __forceinline__ void st4(ushort_t* p, float4 v) {
    us4 h; h.x = f2bf(v.x); h.y = f2bf(v.y); h.z = f2bf(v.z); h.w = f2bf(v.w);
    *(us4*)p = h;
}

// ---------------- twiddle step table for k_f2 / k_i1
__global__ void k_fill_tw(float* __restrict__ ct, float* __restrict__ st) {
    int j = blockIdx.x * 256 + threadIdx.x;   // 0..1023
    float ang = (float)j * (6.283185307179586f / 1024.0f);
    float s, c;
    sincosf(ang, &s, &c);
    ct[j] = c; st[j] = s;
}

// ---------------- T1 table: T1[k2p][y], [2k2][y]=cos(2pi k2 y/1024), [2k2+1][y]=-sin, hi/lo split
__global__ void k_fill_T1(ushort_t* __restrict__ T1h, ushort_t* __restrict__ T1l) {
    int idx = blockIdx.x * 256 + threadIdx.x;   // 0..65535
    int k2p = idx >> 10, y = idx & 1023;
    int k2 = k2p >> 1;
    float ang = (float)((k2 * y) & MASKN) * (6.283185307179586f / 1024.0f);
    float s, c;
    sincosf(ang, &s, &c);
    float v = (k2p & 1) ? -s : c;
    ushort_t h = f2bf(v);
    T1h[idx] = h;
    T1l[idx] = f2bf(v - bf2f(h));
}

// ---------------- T2 table: T2[n2][kk], [n2][2k2]=cos(2pi n2 k2/1024), [n2][2k2+1]=-sin, hi/lo
__global__ void k_fill_T2(ushort_t* __restrict__ T2h, ushort_t* __restrict__ T2l) {
    int idx = blockIdx.x * 256 + threadIdx.x;   // 0..65535
    int n2 = idx >> 6, kk = idx & 63;
    int k2 = kk >> 1;
    float ang = (float)((k2 * n2) & MASKN) * (6.283185307179586f / 1024.0f);
    float s, c;
    sincosf(ang, &s, &c);
    float v = (kk & 1) ? -s : c;
    ushort_t h = f2bf(v);
    T2h[idx] = h;
    T2l[idx] = f2bf(v - bf2f(h));
}

// ---------------- wT tables: wT[l][d][c] = w_l[c][d], hi/lo
__global__ void k_fill_wT(const float* __restrict__ w1, const float* __restrict__ w2,
        const float* __restrict__ w3, const float* __restrict__ w4,
        ushort_t* __restrict__ wTh, ushort_t* __restrict__ wTl) {
    int l = blockIdx.y;
    int i = blockIdx.x * 256 + threadIdx.x;   // 0..4095
    int d = i >> 6, c = i & 63;
    const float* w = (l == 0) ? w1 : (l == 1) ? w2 : (l == 2) ? w3 : w4;
    float v = w[c * 64 + d];
    ushort_t h = f2bf(v);
    wTh[l * 4096 + i] = h;
    wTl[l * 4096 + i] = f2bf(v - bf2f(h));
}

// ---------------- shallow: vt[p][c] = gelu(in[p][0]*Wsh[0][c] + in[p][1]*Wsh[1][c] + bsh[c])
__global__ __launch_bounds__(256) void k_shallow(const float* __restrict__ in,
        const float* __restrict__ Wsh, const float* __restrict__ bsh,
        ushort_t* __restrict__ vt) {
    int tid = blockIdx.x * 256 + threadIdx.x;
    int p = tid >> 4, c0 = (tid & 15) << 2;
    float a0 = in[p * 2], a1 = in[p * 2 + 1];
    float4 w0 = *(const float4*)&Wsh[c0];
    float4 w1 = *(const float4*)&Wsh[64 + c0];
    float4 b  = *(const float4*)&bsh[c0];
    float4 r;
    r.x = gelu_f(fmaf(a0, w0.x, fmaf(a1, w1.x, b.x)));
    r.y = gelu_f(fmaf(a0, w0.y, fmaf(a1, w1.y, b.y)));
    r.z = gelu_f(fmaf(a0, w0.z, fmaf(a1, w1.z, b.z)));
    r.w = gelu_f(fmaf(a0, w0.w, fmaf(a1, w1.w, b.w)));
    st4(&vt[(size_t)p * 64 + c0], r);
}

// ---------------- F1 (MFMA): gT[x][c][k2p] = sum_y vt[x][y][c] * T1[k2p][y]
// block = one x; 4 waves, wave = m-tile of 16 c; K = 1024 y in 8 chunks of 128.
#define F1S 136   // LDS row stride (bf16) for transposed vt tile
__global__ __launch_bounds__(256) void k_f1(const ushort_t* __restrict__ vt,
        const ushort_t* __restrict__ T1h, const ushort_t* __restrict__ T1l,
        float* __restrict__ gT) {
    __shared__ __align__(16) ushort_t vs[64 * F1S];   // 17408 B
    int t = threadIdx.x;
    int x = blockIdx.x;
    int wv = t >> 6, ln = t & 63;
    int lm = ln & 15, quad = ln >> 4;
    int mt = wv;                          // wave's m-tile (16 c rows)
    int lrow = t & 127, chalf = (t >> 7) * 32;   // staging map
    floatx4 acc[4];
    #pragma unroll
    for (int nt = 0; nt < 4; ++nt) acc[nt] = (floatx4)(0.f);
    const ushort_t* vrow = vt + (size_t)x * 65536;
    for (int ch = 0; ch < 8; ++ch) {
        __syncthreads();
        // stage + transpose: vt[y][c] -> vs[c][y] for 128 y x 64 c
        const ushort_t* src = vrow + (size_t)(ch * 128 + lrow) * 64 + chalf;
        #pragma unroll
        for (int i = 0; i < 4; ++i) {
            union { uint4 u; ushort_t e[8]; } uv;
            uv.u = *(const uint4*)(src + i * 8);
            #pragma unroll
            for (int j = 0; j < 8; ++j)
                vs[(chalf + i * 8 + j) * F1S + lrow] = uv.e[j];
        }
        __syncthreads();
        #pragma unroll
        for (int ks = 0; ks < 4; ++ks) {
            short8 af = *(const short8*)&vs[(mt * 16 + lm) * F1S + ks * 32 + quad * 8];
            int ybase = ch * 128 + ks * 32 + quad * 8;
            #pragma unroll
            for (int nt = 0; nt < 4; ++nt) {
                short8 bh = *(const short8*)(T1h + (size_t)(nt * 16 + lm) * 1024 + ybase);
                short8 bl = *(const short8*)(T1l + (size_t)(nt * 16 + lm) * 1024 + ybase);
                acc[nt] = __builtin_amdgcn_mfma_f32_16x16x32_bf16(af, bh, acc[nt], 0, 0, 0);
                acc[nt] = __builtin_amdgcn_mfma_f32_16x16x32_bf16(af, bl, acc[nt], 0, 0, 0);
            }
        }
    }
    // C: row = c = mt*16 + quad*4 + r ; col = k2p = nt*16 + lm
    float* grow = gT + (size_t)x * 4096;
    #pragma unroll
    for (int nt = 0; nt < 4; ++nt)
        #pragma unroll
        for (int r = 0; r < 4; ++r)
            grow[(mt * 16 + quad * 4 + r) * 64 + nt * 16 + lm] = acc[nt][r];
}

// ---------------- F2: fp[cx][k1*32+k2][c] = sum_{x in cx} g[x][k2][c] (x) e^{-2pi i k1 x/1024}
// reads gT[x][c][k2p] coalesced; re/im pairing via shfl_xor; register twiddle rotation.
__global__ __launch_bounds__(256) void k_f2(const float* __restrict__ gT,
        const float* __restrict__ ct, const float* __restrict__ st,
        float* __restrict__ fpr, float* __restrict__ fpi) {
    int t = threadIdx.x;
    int cx = blockIdx.x;          // 0..7
    int cg = blockIdx.y;          // 0..15
    int l = t & 63;               // k2p
    int q = t >> 6;               // 0..3
    int c = cg * 4 + q;
    int e = l & 1;                // 0 = re lane, 1 = im lane
    int k2 = l >> 1;
    float acc[32];
    #pragma unroll
    for (int i = 0; i < 32; ++i) acc[i] = 0.f;
    for (int xi = 0; xi < 128; ++xi) {
        int x = cx * 128 + xi;
        float v = gT[(size_t)x * 4096 + c * 64 + l];
        float p = __shfl_xor(v, 1);
        float gr = e ? p : v;
        float gi = e ? v : p;
        float u  = e ? gi : gr;
        float w2 = e ? -gr : gi;
        float cb = ct[x], sb = st[x];
        float cr = 1.f, sr = 0.f;
        #pragma unroll
        for (int k1 = 0; k1 < 32; ++k1) {
            acc[k1] = fmaf(u, cr, fmaf(w2, sr, acc[k1]));
            float nc = fmaf(cr, cb, -sr * sb);
            float ns = fmaf(sr, cb, cr * sb);
            cr = nc; sr = ns;
        }
    }
    float* dst = e ? fpi : fpr;
    #pragma unroll
    for (int k1 = 0; k1 < 32; ++k1)
        dst[(size_t)cx * 65536 + (k1 * 32 + k2) * 64 + c] = acc[k1];
}

// ---------------- MIX: Rf[m,d] = sum_c f[m,c] * (Rr+iRi)[m,c,d], f = sum of 8 partials
__global__ __launch_bounds__(64) void k_mix(const float* __restrict__ fpr, const float* __restrict__ fpi,
        const float* __restrict__ Rr, const float* __restrict__ Ri,
        float* __restrict__ Rfr, float* __restrict__ Rfi) {
    __shared__ float fr[64], fi[64];
    int m = blockIdx.x;
    int d = threadIdx.x;
    float sr = 0.f, si = 0.f;
    #pragma unroll
    for (int ch = 0; ch < 8; ++ch) {
        sr += fpr[(size_t)ch * 65536 + m * 64 + d];
        si += fpi[(size_t)ch * 65536 + m * 64 + d];
    }
    fr[d] = sr; fi[d] = si;
    __syncthreads();
    const float* Rrb = Rr + (size_t)m * 4096;
    const float* Rib = Ri + (size_t)m * 4096;
    float ar = 0.f, ai = 0.f;
    for (int c = 0; c < 64; ++c) {
        float rr = Rrb[c * 64 + d], ri = Rib[c * 64 + d];
        ar = fmaf(fr[c], rr, fmaf(-fi[c], ri, ar));
        ai = fmaf(fr[c], ri, fmaf(fi[c], rr, ai));
    }
    Rfr[m * 64 + d] = ar;
    Rfi[m * 64 + d] = ai;
}

// ---------------- I1: Bmat[n1][d][kk] (bf16 hi/lo, kk = 2k2(+1) = re/im interleaved)
// B[n1][k2] = w_k2/2^20 * sum_k1 Rf[k1,k2] * e^{+2pi i k1 n1/1024}
__global__ __launch_bounds__(256) void k_i1(const float* __restrict__ Rfr, const float* __restrict__ Rfi,
        const float* __restrict__ ctg, const float* __restrict__ stg,
        ushort_t* __restrict__ Bh, ushort_t* __restrict__ Bl) {
    __shared__ float ct[1024], st[1024];
    int t = threadIdx.x;
    #pragma unroll
    for (int i = 0; i < 4; ++i) { int j = t + 256 * i; ct[j] = ctg[j]; st[j] = stg[j]; }
    __syncthreads();
    int n1 = blockIdx.x;
    int d = t & 63;
    int k20 = (t >> 6) * 8;
    float br[8], bi[8];
    #pragma unroll
    for (int j = 0; j < 8; ++j) { br[j] = 0.f; bi[j] = 0.f; }
    int idx = 0;
    for (int k1 = 0; k1 < 32; ++k1) {
        float cc = ct[idx], ss = st[idx];
        idx = (idx + n1) & MASKN;
        #pragma unroll
        for (int j = 0; j < 8; ++j) {
            float rr = Rfr[(k1 * 32 + k20 + j) * 64 + d];
            float ri = Rfi[(k1 * 32 + k20 + j) * 64 + d];
            br[j] = fmaf(rr, cc, fmaf(-ri, ss, br[j]));
            bi[j] = fmaf(rr, ss, fmaf(ri, cc, bi[j]));
        }
    }
    union { uint4 u[2]; ushort_t e[16]; } hh, ll;
    #pragma unroll
    for (int j = 0; j < 8; ++j) {
        int k2 = k20 + j;
        float sc = (k2 == 0 ? 1.0f : 2.0f) * 9.5367431640625e-7f;   // 1/2^20
        float vr = br[j] * sc, vi = bi[j] * sc;
        ushort_t hr = f2bf(vr), hi2 = f2bf(vi);
        hh.e[2 * j] = hr;          hh.e[2 * j + 1] = hi2;
        ll.e[2 * j] = f2bf(vr - bf2f(hr));
        ll.e[2 * j + 1] = f2bf(vi - bf2f(hi2));
    }
    size_t base = ((size_t)n1 * 64 + d) * 64 + 2 * k20;
    *(uint4*)(Bh + base) = hh.u[0];
    *(uint4*)(Bh + base + 8) = hh.u[1];
    *(uint4*)(Bl + base) = ll.u[0];
    *(uint4*)(Bl + base + 8) = ll.u[1];
}

// ---------------- I2 (MFMA, fused): vt[n1][n2][d] = gelu( T2[n2,:]@Bmat[n1][:, d] + vt[n1][n2,:]@w[:,d] )
// grid (8 n2-chunks, 1024 n1); 4 waves; wave = 32 n2 x 64 d; no LDS, no barriers.
__global__ __launch_bounds__(256) void k_i2(ushort_t* __restrict__ vt,
        const ushort_t* __restrict__ Bh, const ushort_t* __restrict__ Bl,
        const ushort_t* __restrict__ T2h, const ushort_t* __restrict__ T2l,
        const ushort_t* __restrict__ wTh, const ushort_t* __restrict__ wTl) {
    int t = threadIdx.x;
    int wv = t >> 6, ln = t & 63;
    int lm = ln & 15, quad = ln >> 4;
    int chunk = blockIdx.x, n1 = blockIdx.y;
    int n2b = chunk * 128 + wv * 32;
    const ushort_t* Bhr = Bh + (size_t)n1 * 4096;
    const ushort_t* Blr = Bl + (size_t)n1 * 4096;
    ushort_t* vrow = vt + ((size_t)n1 * 1024 + n2b) * 64;
    floatx4 acc[2][4];
    #pragma unroll
    for (int m = 0; m < 2; ++m)
        #pragma unroll
        for (int nt = 0; nt < 4; ++nt) acc[m][nt] = (floatx4)(0.f);
    // phase 1: T2 x Bmat  (hi*hi + lo*hi + hi*lo)
    #pragma unroll
    for (int ks = 0; ks < 2; ++ks) {
        int kk = ks * 32 + quad * 8;
        short8 a0h = *(const short8*)(T2h + (size_t)(n2b + lm) * 64 + kk);
        short8 a1h = *(const short8*)(T2h + (size_t)(n2b + 16 + lm) * 64 + kk);
        short8 a0l = *(const short8*)(T2l + (size_t)(n2b + lm) * 64 + kk);
        short8 a1l = *(const short8*)(T2l + (size_t)(n2b + 16 + lm) * 64 + kk);
        #pragma unroll
        for (int nt = 0; nt < 4; ++nt) {
            short8 bh = *(const short8*)(Bhr + (nt * 16 + lm) * 64 + kk);
            short8 bl = *(const short8*)(Blr + (nt * 16 + lm) * 64 + kk);
            acc[0][nt] = __builtin_amdgcn_mfma_f32_16x16x32_bf16(a0h, bh, acc[0][nt], 0, 0, 0);
            acc[1][nt] = __builtin_amdgcn_mfma_f32_16x16x32_bf16(a1h, bh, acc[1][nt], 0, 0, 0);
            acc[0][nt] = __builtin_amdgcn_mfma_f32_16x16x32_bf16(a0l, bh, acc[0][nt], 0, 0, 0);
            acc[1][nt] = __builtin_amdgcn_mfma_f32_16x16x32_bf16(a1l, bh, acc[1][nt], 0, 0, 0);
            acc[0][nt] = __builtin_amdgcn_mfma_f32_16x16x32_bf16(a0h, bl, acc[0][nt], 0, 0, 0);
            acc[1][nt] = __builtin_amdgcn_mfma_f32_16x16x32_bf16(a1h, bl, acc[1][nt], 0, 0, 0);
        }
    }
    // phase 2: vt x w  (vt * (wh + wl))
    #pragma unroll
    for (int ks = 0; ks < 2; ++ks) {
        int cc = ks * 32 + quad * 8;
        short8 a0 = *(const short8*)(vrow + (size_t)lm * 64 + cc);
        short8 a1 = *(const short8*)(vrow + (size_t)(16 + lm) * 64 + cc);
        #pragma unroll
        for (int nt = 0; nt < 4; ++nt) {
            short8 bh = *(const short8*)(wTh + (nt * 16 + lm) * 64 + cc);
            short8 bl = *(const short8*)(wTl + (nt * 16 + lm) * 64 + cc);
            acc[0][nt] = __builtin_amdgcn_mfma_f32_16x16x32_bf16(a0, bh, acc[0][nt], 0, 0, 0);
            acc[1][nt] = __builtin_amdgcn_mfma_f32_16x16x32_bf16(a1, bh, acc[1][nt], 0, 0, 0);
            acc[0][nt] = __builtin_amdgcn_mfma_f32_16x16x32_bf16(a0, bl, acc[0][nt], 0, 0, 0);
            acc[1][nt] = __builtin_amdgcn_mfma_f32_16x16x32_bf16(a1, bl, acc[1][nt], 0, 0, 0);
        }
    }
    // epilogue: gelu + bf16 store; row = mt*16 + quad*4 + r, col d = nt*16 + lm
    #pragma unroll
    for (int m = 0; m < 2; ++m)
        #pragma unroll
        for (int nt = 0; nt < 4; ++nt)
            #pragma unroll
            for (int r = 0; r < 4; ++r)
                vrow[(size_t)(m * 16 + quad * 4 + r) * 64 + nt * 16 + lm] = f2bf(gelu_f(acc[m][nt][r]));
}

// ---------------- projection: out[p] = sum_c vt[p,c]*Wp[c] + bp[0]
__global__ __launch_bounds__(256) void k_proj(const ushort_t* __restrict__ vt,
        const float* __restrict__ Wp, const float* __restrict__ bp,
        float* __restrict__ out) {
    __shared__ float wp[64];
    int t = threadIdx.x;
    if (t < 64) wp[t] = Wp[t];
    __syncthreads();
    int p = blockIdx.x * 256 + t;
    const ushort_t* v = vt + (size_t)p * 64;
    float acc = bp[0];
    #pragma unroll
    for (int i = 0; i < 16; ++i) {
        us4 a = *(const us4*)&v[i * 4];
        acc = fmaf(bf2f(a.x), wp[i * 4 + 0], acc);
        acc = fmaf(bf2f(a.y), wp[i * 4 + 1], acc);
        acc = fmaf(bf2f(a.z), wp[i * 4 + 2], acc);
        acc = fmaf(bf2f(a.w), wp[i * 4 + 3], acc);
    }
    out[p] = acc;
}

extern "C" void kernel_launch(void* const* d_in, const int* in_sizes, int n_in,
                              void* d_out, int out_size, void* d_ws, size_t ws_size,
                              hipStream_t stream) {
    const float* in  = (const float*)d_in[0];
    const float* Wsh = (const float*)d_in[1];
    const float* bsh = (const float*)d_in[2];
    const float* Wp  = (const float*)d_in[15];
    const float* bp  = (const float*)d_in[16];

    // workspace layout (~151.9 MB, proven fits: previous 155.7 MB layout ran)
    char* wsb = (char*)d_ws;
    ushort_t* vt   = (ushort_t*)wsb;                          // 1024*1024*64 bf16 = 134,217,728 B
    float* ctab = (float*)(wsb + 134217728);                  // 1024
    float* stab = ctab + 1024;                                // 1024
    float* gT   = stab + 1024;                                // 1024*64*64 f32 = 16 MB
    float* Rfr  = gT + 4194304;                               // 65536
    float* Rfi  = Rfr + 65536;                                // 65536
    ushort_t* T1h = (ushort_t*)(Rfi + 65536);                 // 64*1024
    ushort_t* T1l = T1h + 65536;
    ushort_t* T2h = T1l + 65536;                              // 1024*64
    ushort_t* T2l = T2h + 65536;
    ushort_t* wTh = T2l + 65536;                              // 4*64*64
    ushort_t* wTl = wTh + 16384;
    ushort_t* Bh  = (ushort_t*)gT;                            // alias gT (dead after k_f2)
    ushort_t* Bl  = Bh + 4194304;
    float* fpr = (float*)d_out;                               // alias d_out (dead before k_proj)
    float* fpi = fpr + 524288;

    k_fill_tw<<<4, 256, 0, stream>>>(ctab, stab);
    k_fill_T1<<<256, 256, 0, stream>>>(T1h, T1l);
    k_fill_T2<<<256, 256, 0, stream>>>(T2h, T2l);
    k_fill_wT<<<dim3(16, 4), 256, 0, stream>>>((const float*)d_in[5], (const float*)d_in[8],
                                               (const float*)d_in[11], (const float*)d_in[14], wTh, wTl);
    k_shallow<<<65536, 256, 0, stream>>>(in, Wsh, bsh, vt);
    for (int L = 0; L < 4; ++L) {
        const float* Rr = (const float*)d_in[3 + L * 3];
        const float* Ri = (const float*)d_in[4 + L * 3];
        k_f1<<<1024, 256, 0, stream>>>(vt, T1h, T1l, gT);
        k_f2<<<dim3(8, 16), 256, 0, stream>>>(gT, ctab, stab, fpr, fpi);
        k_mix<<<1024, 64, 0, stream>>>(fpr, fpi, Rr, Ri, Rfr, Rfi);
        k_i1<<<1024, 256, 0, stream>>>(Rfr, Rfi, ctab, stab, Bh, Bl);
        k_i2<<<dim3(8, 1024), 256, 0, stream>>>(vt, Bh, Bl, T2h, T2l, wTh + L * 4096, wTl + L * 4096);
    }
    k_proj<<<4096, 256, 0, stream>>>(vt, Wp, bp, (float*)d_out);
}

// Round 4
// 1763.640 us; speedup vs baseline: 1.3153x; 1.0664x over previous
//
#include <hip/hip_runtime.h>
#include <math.h>

#define MASKN 1023

typedef unsigned short ushort_t;
typedef __attribute__((ext_vector_type(8))) short short8;
typedef __attribute__((ext_vector_type(4))) float floatx4;

__device__ __forceinline__ float gelu_f(float x) {
    return 0.5f * x * (1.0f + erff(x * 0.7071067811865475f));
}

// ---- bf16 storage helpers (compute stays fp32) ----
__device__ __forceinline__ float bf2f(ushort_t h) {
    return __uint_as_float(((unsigned int)h) << 16);
}
__device__ __forceinline__ ushort_t f2bf(float f) {
    unsigned int u = __float_as_uint(f);
    u += 0x7FFFu + ((u >> 16) & 1u);   // round to nearest even
    return (ushort_t)(u >> 16);
}
struct us4 { ushort_t x, y, z, w; };

__device__ __forceinline__ void st4(ushort_t* p, float4 v) {
    us4 h; h.x = f2bf(v.x); h.y = f2bf(v.y); h.z = f2bf(v.z); h.w = f2bf(v.w);
    *(us4*)p = h;
}

// ---------------- twiddle step table for k_f2 / k_i1
__global__ void k_fill_tw(float* __restrict__ ct, float* __restrict__ st) {
    int j = blockIdx.x * 256 + threadIdx.x;   // 0..1023
    float ang = (float)j * (6.283185307179586f / 1024.0f);
    float s, c;
    sincosf(ang, &s, &c);
    ct[j] = c; st[j] = s;
}

// ---------------- T1 table: T1[k2p][y], [2k2][y]=cos(2pi k2 y/1024), [2k2+1][y]=-sin, hi/lo split
__global__ void k_fill_T1(ushort_t* __restrict__ T1h, ushort_t* __restrict__ T1l) {
    int idx = blockIdx.x * 256 + threadIdx.x;   // 0..65535
    int k2p = idx >> 10, y = idx & 1023;
    int k2 = k2p >> 1;
    float ang = (float)((k2 * y) & MASKN) * (6.283185307179586f / 1024.0f);
    float s, c;
    sincosf(ang, &s, &c);
    float v = (k2p & 1) ? -s : c;
    ushort_t h = f2bf(v);
    T1h[idx] = h;
    T1l[idx] = f2bf(v - bf2f(h));
}

// ---------------- T2 table: T2[n2][kk], [n2][2k2]=cos(2pi n2 k2/1024), [n2][2k2+1]=-sin, hi/lo
__global__ void k_fill_T2(ushort_t* __restrict__ T2h, ushort_t* __restrict__ T2l) {
    int idx = blockIdx.x * 256 + threadIdx.x;   // 0..65535
    int n2 = idx >> 6, kk = idx & 63;
    int k2 = kk >> 1;
    float ang = (float)((k2 * n2) & MASKN) * (6.283185307179586f / 1024.0f);
    float s, c;
    sincosf(ang, &s, &c);
    float v = (kk & 1) ? -s : c;
    ushort_t h = f2bf(v);
    T2h[idx] = h;
    T2l[idx] = f2bf(v - bf2f(h));
}

// ---------------- wT tables: wT[l][d][c] = w_l[c][d], hi/lo
__global__ void k_fill_wT(const float* __restrict__ w1, const float* __restrict__ w2,
        const float* __restrict__ w3, const float* __restrict__ w4,
        ushort_t* __restrict__ wTh, ushort_t* __restrict__ wTl) {
    int l = blockIdx.y;
    int i = blockIdx.x * 256 + threadIdx.x;   // 0..4095
    int d = i >> 6, c = i & 63;
    const float* w = (l == 0) ? w1 : (l == 1) ? w2 : (l == 2) ? w3 : w4;
    float v = w[c * 64 + d];
    ushort_t h = f2bf(v);
    wTh[l * 4096 + i] = h;
    wTl[l * 4096 + i] = f2bf(v - bf2f(h));
}

// ---------------- shallow: vt[p][c] = gelu(in[p][0]*Wsh[0][c] + in[p][1]*Wsh[1][c] + bsh[c])
__global__ __launch_bounds__(256) void k_shallow(const float* __restrict__ in,
        const float* __restrict__ Wsh, const float* __restrict__ bsh,
        ushort_t* __restrict__ vt) {
    int tid = blockIdx.x * 256 + threadIdx.x;
    int p = tid >> 4, c0 = (tid & 15) << 2;
    float a0 = in[p * 2], a1 = in[p * 2 + 1];
    float4 w0 = *(const float4*)&Wsh[c0];
    float4 w1 = *(const float4*)&Wsh[64 + c0];
    float4 b  = *(const float4*)&bsh[c0];
    float4 r;
    r.x = gelu_f(fmaf(a0, w0.x, fmaf(a1, w1.x, b.x)));
    r.y = gelu_f(fmaf(a0, w0.y, fmaf(a1, w1.y, b.y)));
    r.z = gelu_f(fmaf(a0, w0.z, fmaf(a1, w1.z, b.z)));
    r.w = gelu_f(fmaf(a0, w0.w, fmaf(a1, w1.w, b.w)));
    st4(&vt[(size_t)p * 64 + c0], r);
}

// ---------------- F1 (standalone, MFMA): gT[x][c][k2p] = sum_y vt[x][y][c] * T1[k2p][y]
#define F1S 136   // LDS row stride (bf16) for transposed vt tile
__global__ __launch_bounds__(256) void k_f1(const ushort_t* __restrict__ vt,
        const ushort_t* __restrict__ T1h, const ushort_t* __restrict__ T1l,
        float* __restrict__ gT) {
    __shared__ __align__(16) ushort_t vs[64 * F1S];   // 17408 B
    int t = threadIdx.x;
    int x = blockIdx.x;
    int wv = t >> 6, ln = t & 63;
    int lm = ln & 15, quad = ln >> 4;
    int mt = wv;                          // wave's m-tile (16 c rows)
    int lrow = t & 127, chalf = (t >> 7) * 32;   // staging map
    floatx4 acc[4];
    #pragma unroll
    for (int nt = 0; nt < 4; ++nt) acc[nt] = (floatx4)(0.f);
    const ushort_t* vrow = vt + (size_t)x * 65536;
    for (int ch = 0; ch < 8; ++ch) {
        __syncthreads();
        const ushort_t* src = vrow + (size_t)(ch * 128 + lrow) * 64 + chalf;
        #pragma unroll
        for (int i = 0; i < 4; ++i) {
            union { uint4 u; ushort_t e[8]; } uv;
            uv.u = *(const uint4*)(src + i * 8);
            #pragma unroll
            for (int j = 0; j < 8; ++j)
                vs[(chalf + i * 8 + j) * F1S + lrow] = uv.e[j];
        }
        __syncthreads();
        #pragma unroll
        for (int ks = 0; ks < 4; ++ks) {
            short8 af = *(const short8*)&vs[(mt * 16 + lm) * F1S + ks * 32 + quad * 8];
            int ybase = ch * 128 + ks * 32 + quad * 8;
            #pragma unroll
            for (int nt = 0; nt < 4; ++nt) {
                short8 bh = *(const short8*)(T1h + (size_t)(nt * 16 + lm) * 1024 + ybase);
                short8 bl = *(const short8*)(T1l + (size_t)(nt * 16 + lm) * 1024 + ybase);
                acc[nt] = __builtin_amdgcn_mfma_f32_16x16x32_bf16(af, bh, acc[nt], 0, 0, 0);
                acc[nt] = __builtin_amdgcn_mfma_f32_16x16x32_bf16(af, bl, acc[nt], 0, 0, 0);
            }
        }
    }
    float* grow = gT + (size_t)x * 4096;
    #pragma unroll
    for (int nt = 0; nt < 4; ++nt)
        #pragma unroll
        for (int r = 0; r < 4; ++r)
            grow[(mt * 16 + quad * 4 + r) * 64 + nt * 16 + lm] = acc[nt][r];
}

// ---------------- F2: fp[cx][k1*32+k2][c] = sum_{x in cx} g[x][k2][c] (x) e^{-2pi i k1 x/1024}
__global__ __launch_bounds__(256) void k_f2(const float* __restrict__ gT,
        const float* __restrict__ ct, const float* __restrict__ st,
        float* __restrict__ fpr, float* __restrict__ fpi) {
    int t = threadIdx.x;
    int cx = blockIdx.x;          // 0..7
    int cg = blockIdx.y;          // 0..15
    int l = t & 63;               // k2p
    int q = t >> 6;               // 0..3
    int c = cg * 4 + q;
    int e = l & 1;                // 0 = re lane, 1 = im lane
    int k2 = l >> 1;
    float acc[32];
    #pragma unroll
    for (int i = 0; i < 32; ++i) acc[i] = 0.f;
    for (int xi = 0; xi < 128; ++xi) {
        int x = cx * 128 + xi;
        float v = gT[(size_t)x * 4096 + c * 64 + l];
        float p = __shfl_xor(v, 1);
        float gr = e ? p : v;
        float gi = e ? v : p;
        float u  = e ? gi : gr;
        float w2 = e ? -gr : gi;
        float cb = ct[x], sb = st[x];
        float cr = 1.f, sr = 0.f;
        #pragma unroll
        for (int k1 = 0; k1 < 32; ++k1) {
            acc[k1] = fmaf(u, cr, fmaf(w2, sr, acc[k1]));
            float nc = fmaf(cr, cb, -sr * sb);
            float ns = fmaf(sr, cb, cr * sb);
            cr = nc; sr = ns;
        }
    }
    float* dst = e ? fpi : fpr;
    #pragma unroll
    for (int k1 = 0; k1 < 32; ++k1)
        dst[(size_t)cx * 65536 + (k1 * 32 + k2) * 64 + c] = acc[k1];
}

// ---------------- MIX: Rf[m,d] = sum_c f[m,c] * (Rr+iRi)[m,c,d], f = sum of 8 partials
__global__ __launch_bounds__(64) void k_mix(const float* __restrict__ fpr, const float* __restrict__ fpi,
        const float* __restrict__ Rr, const float* __restrict__ Ri,
        float* __restrict__ Rfr, float* __restrict__ Rfi) {
    __shared__ float fr[64], fi[64];
    int m = blockIdx.x;
    int d = threadIdx.x;
    float sr = 0.f, si = 0.f;
    #pragma unroll
    for (int ch = 0; ch < 8; ++ch) {
        sr += fpr[(size_t)ch * 65536 + m * 64 + d];
        si += fpi[(size_t)ch * 65536 + m * 64 + d];
    }
    fr[d] = sr; fi[d] = si;
    __syncthreads();
    const float* Rrb = Rr + (size_t)m * 4096;
    const float* Rib = Ri + (size_t)m * 4096;
    float ar = 0.f, ai = 0.f;
    for (int c = 0; c < 64; ++c) {
        float rr = Rrb[c * 64 + d], ri = Rib[c * 64 + d];
        ar = fmaf(fr[c], rr, fmaf(-fi[c], ri, ar));
        ai = fmaf(fr[c], ri, fmaf(fi[c], rr, ai));
    }
    Rfr[m * 64 + d] = ar;
    Rfi[m * 64 + d] = ai;
}

// ---------------- I1: Bmat[n1][d][kk] (bf16 hi/lo, kk = 2k2(+1) = re/im interleaved)
__global__ __launch_bounds__(256) void k_i1(const float* __restrict__ Rfr, const float* __restrict__ Rfi,
        const float* __restrict__ ctg, const float* __restrict__ stg,
        ushort_t* __restrict__ Bh, ushort_t* __restrict__ Bl) {
    __shared__ float ct[1024], st[1024];
    int t = threadIdx.x;
    #pragma unroll
    for (int i = 0; i < 4; ++i) { int j = t + 256 * i; ct[j] = ctg[j]; st[j] = stg[j]; }
    __syncthreads();
    int n1 = blockIdx.x;
    int d = t & 63;
    int k20 = (t >> 6) * 8;
    float br[8], bi[8];
    #pragma unroll
    for (int j = 0; j < 8; ++j) { br[j] = 0.f; bi[j] = 0.f; }
    int idx = 0;
    for (int k1 = 0; k1 < 32; ++k1) {
        float cc = ct[idx], ss = st[idx];
        idx = (idx + n1) & MASKN;
        #pragma unroll
        for (int j = 0; j < 8; ++j) {
            float rr = Rfr[(k1 * 32 + k20 + j) * 64 + d];
            float ri = Rfi[(k1 * 32 + k20 + j) * 64 + d];
            br[j] = fmaf(rr, cc, fmaf(-ri, ss, br[j]));
            bi[j] = fmaf(rr, ss, fmaf(ri, cc, bi[j]));
        }
    }
    union { uint4 u[2]; ushort_t e[16]; } hh, ll;
    #pragma unroll
    for (int j = 0; j < 8; ++j) {
        int k2 = k20 + j;
        float sc = (k2 == 0 ? 1.0f : 2.0f) * 9.5367431640625e-7f;   // 1/2^20
        float vr = br[j] * sc, vi = bi[j] * sc;
        ushort_t hr = f2bf(vr), hi2 = f2bf(vi);
        hh.e[2 * j] = hr;          hh.e[2 * j + 1] = hi2;
        ll.e[2 * j] = f2bf(vr - bf2f(hr));
        ll.e[2 * j + 1] = f2bf(vi - bf2f(hi2));
    }
    size_t base = ((size_t)n1 * 64 + d) * 64 + 2 * k20;
    *(uint4*)(Bh + base) = hh.u[0];
    *(uint4*)(Bh + base + 8) = hh.u[1];
    *(uint4*)(Bl + base) = ll.u[0];
    *(uint4*)(Bl + base + 8) = ll.u[1];
}

// ---------------- I2 fused with next layer's F1.
// One block per n1 row; 8 chunks of 128 n2. Per chunk: MFMA i2 (T2@B + vt@w),
// gelu epilogue -> global vt + transposed LDS tile; then accumulate
// gT_next[n1][c][k2p] += vs[c][y] @ T1[k2p][y] across chunks (if gT != null).
#define I2S 136
__global__ __launch_bounds__(256) void k_i2f(ushort_t* __restrict__ vt,
        const ushort_t* __restrict__ Bh, const ushort_t* __restrict__ Bl,
        const ushort_t* __restrict__ T2h, const ushort_t* __restrict__ T2l,
        const ushort_t* __restrict__ wTh, const ushort_t* __restrict__ wTl,
        const ushort_t* __restrict__ T1h, const ushort_t* __restrict__ T1l,
        float* __restrict__ gT) {
    __shared__ __align__(16) ushort_t vs[2][64 * I2S];   // 2 x 17408 B
    int t = threadIdx.x;
    int wv = t >> 6, ln = t & 63;
    int lm = ln & 15, quad = ln >> 4;
    int n1 = blockIdx.x;
    const ushort_t* Bhr = Bh + (size_t)n1 * 4096;
    const ushort_t* Blr = Bl + (size_t)n1 * 4096;
    bool dof1 = (gT != nullptr);
    floatx4 gacc[4];
    #pragma unroll
    for (int nt = 0; nt < 4; ++nt) gacc[nt] = (floatx4)(0.f);

    for (int ch = 0; ch < 8; ++ch) {
        int n2b = ch * 128 + wv * 32;
        ushort_t* vrow = vt + ((size_t)n1 * 1024 + n2b) * 64;
        floatx4 acc[2][4];
        #pragma unroll
        for (int m = 0; m < 2; ++m)
            #pragma unroll
            for (int nt = 0; nt < 4; ++nt) acc[m][nt] = (floatx4)(0.f);
        // phase 1: T2 x Bmat  (hi*hi + lo*hi + hi*lo)
        #pragma unroll
        for (int ks = 0; ks < 2; ++ks) {
            int kk = ks * 32 + quad * 8;
            short8 a0h = *(const short8*)(T2h + (size_t)(n2b + lm) * 64 + kk);
            short8 a1h = *(const short8*)(T2h + (size_t)(n2b + 16 + lm) * 64 + kk);
            short8 a0l = *(const short8*)(T2l + (size_t)(n2b + lm) * 64 + kk);
            short8 a1l = *(const short8*)(T2l + (size_t)(n2b + 16 + lm) * 64 + kk);
            #pragma unroll
            for (int nt = 0; nt < 4; ++nt) {
                short8 bh = *(const short8*)(Bhr + (nt * 16 + lm) * 64 + kk);
                short8 bl = *(const short8*)(Blr + (nt * 16 + lm) * 64 + kk);
                acc[0][nt] = __builtin_amdgcn_mfma_f32_16x16x32_bf16(a0h, bh, acc[0][nt], 0, 0, 0);
                acc[1][nt] = __builtin_amdgcn_mfma_f32_16x16x32_bf16(a1h, bh, acc[1][nt], 0, 0, 0);
                acc[0][nt] = __builtin_amdgcn_mfma_f32_16x16x32_bf16(a0l, bh, acc[0][nt], 0, 0, 0);
                acc[1][nt] = __builtin_amdgcn_mfma_f32_16x16x32_bf16(a1l, bh, acc[1][nt], 0, 0, 0);
                acc[0][nt] = __builtin_amdgcn_mfma_f32_16x16x32_bf16(a0h, bl, acc[0][nt], 0, 0, 0);
                acc[1][nt] = __builtin_amdgcn_mfma_f32_16x16x32_bf16(a1h, bl, acc[1][nt], 0, 0, 0);
            }
        }
        // phase 2: vt x w
        #pragma unroll
        for (int ks = 0; ks < 2; ++ks) {
            int cc = ks * 32 + quad * 8;
            short8 a0 = *(const short8*)(vrow + (size_t)lm * 64 + cc);
            short8 a1 = *(const short8*)(vrow + (size_t)(16 + lm) * 64 + cc);
            #pragma unroll
            for (int nt = 0; nt < 4; ++nt) {
                short8 bh = *(const short8*)(wTh + (nt * 16 + lm) * 64 + cc);
                short8 bl = *(const short8*)(wTl + (nt * 16 + lm) * 64 + cc);
                acc[0][nt] = __builtin_amdgcn_mfma_f32_16x16x32_bf16(a0, bh, acc[0][nt], 0, 0, 0);
                acc[1][nt] = __builtin_amdgcn_mfma_f32_16x16x32_bf16(a1, bh, acc[1][nt], 0, 0, 0);
                acc[0][nt] = __builtin_amdgcn_mfma_f32_16x16x32_bf16(a0, bl, acc[0][nt], 0, 0, 0);
                acc[1][nt] = __builtin_amdgcn_mfma_f32_16x16x32_bf16(a1, bl, acc[1][nt], 0, 0, 0);
            }
        }
        // epilogue: gelu + bf16 store to global, and transposed LDS tile for f1
        ushort_t* vsb = vs[ch & 1];
        #pragma unroll
        for (int m = 0; m < 2; ++m)
            #pragma unroll
            for (int nt = 0; nt < 4; ++nt)
                #pragma unroll
                for (int r = 0; r < 4; ++r) {
                    ushort_t h = f2bf(gelu_f(acc[m][nt][r]));
                    int row = m * 16 + quad * 4 + r;            // n2 local to wave
                    vrow[(size_t)row * 64 + nt * 16 + lm] = h;
                    if (dof1)
                        vsb[(nt * 16 + lm) * I2S + wv * 32 + row] = h;
                }
        __syncthreads();
        if (dof1) {
            #pragma unroll
            for (int ks = 0; ks < 4; ++ks) {
                short8 af = *(const short8*)&vsb[(wv * 16 + lm) * I2S + ks * 32 + quad * 8];
                int ybase = ch * 128 + ks * 32 + quad * 8;
                #pragma unroll
                for (int nt = 0; nt < 4; ++nt) {
                    short8 bh = *(const short8*)(T1h + (size_t)(nt * 16 + lm) * 1024 + ybase);
                    short8 bl = *(const short8*)(T1l + (size_t)(nt * 16 + lm) * 1024 + ybase);
                    gacc[nt] = __builtin_amdgcn_mfma_f32_16x16x32_bf16(af, bh, gacc[nt], 0, 0, 0);
                    gacc[nt] = __builtin_amdgcn_mfma_f32_16x16x32_bf16(af, bl, gacc[nt], 0, 0, 0);
                }
            }
        }
    }
    if (dof1) {
        float* grow = gT + (size_t)n1 * 4096;
        #pragma unroll
        for (int nt = 0; nt < 4; ++nt)
            #pragma unroll
            for (int r = 0; r < 4; ++r)
                grow[(wv * 16 + quad * 4 + r) * 64 + nt * 16 + lm] = gacc[nt][r];
    }
}

// ---------------- projection: out[p] = sum_c vt[p,c]*Wp[c] + bp[0]
__global__ __launch_bounds__(256) void k_proj(const ushort_t* __restrict__ vt,
        const float* __restrict__ Wp, const float* __restrict__ bp,
        float* __restrict__ out) {
    __shared__ float wp[64];
    int t = threadIdx.x;
    if (t < 64) wp[t] = Wp[t];
    __syncthreads();
    int p = blockIdx.x * 256 + t;
    const ushort_t* v = vt + (size_t)p * 64;
    float acc = bp[0];
    #pragma unroll
    for (int i = 0; i < 16; ++i) {
        us4 a = *(const us4*)&v[i * 4];
        acc = fmaf(bf2f(a.x), wp[i * 4 + 0], acc);
        acc = fmaf(bf2f(a.y), wp[i * 4 + 1], acc);
        acc = fmaf(bf2f(a.z), wp[i * 4 + 2], acc);
        acc = fmaf(bf2f(a.w), wp[i * 4 + 3], acc);
    }
    out[p] = acc;
}

extern "C" void kernel_launch(void* const* d_in, const int* in_sizes, int n_in,
                              void* d_out, int out_size, void* d_ws, size_t ws_size,
                              hipStream_t stream) {
    const float* in  = (const float*)d_in[0];
    const float* Wsh = (const float*)d_in[1];
    const float* bsh = (const float*)d_in[2];
    const float* Wp  = (const float*)d_in[15];
    const float* bp  = (const float*)d_in[16];

    // ---- workspace layout ----
    char* wsb = (char*)d_ws;
    ushort_t* vt = (ushort_t*)wsb;                     // 134,217,728 B
    char* p = wsb + 134217728;
    float* gT = (float*)p;          p += 16777216;     // 1024*64*64 f32
    char* bregion_fused = p;                           // +16,777,216 if fused
    // tail (placed after deciding B region)
    const size_t TAIL = 524288 + 8192 + 262144 + 262144 + 65536;  // Rf + tw + T1 + T2 + wT
    const size_t NEED_FUSED = 134217728ull + 16777216ull + 16777216ull + TAIL;
    bool fused = (ws_size >= NEED_FUSED);

    ushort_t *Bh, *Bl;
    char* q;
    if (fused) {
        Bh = (ushort_t*)bregion_fused;                 // separate 16 MB
        Bl = Bh + 4194304;
        q = bregion_fused + 16777216;
    } else {
        Bh = (ushort_t*)gT;                            // alias gT (dead after k_f2)
        Bl = Bh + 4194304;
        q = bregion_fused;
    }
    float* Rfr  = (float*)q;        q += 262144;
    float* Rfi  = (float*)q;        q += 262144;
    float* ctab = (float*)q;        q += 4096;
    float* stab = (float*)q;        q += 4096;
    ushort_t* T1h = (ushort_t*)q;   q += 131072;
    ushort_t* T1l = (ushort_t*)q;   q += 131072;
    ushort_t* T2h = (ushort_t*)q;   q += 131072;
    ushort_t* T2l = (ushort_t*)q;   q += 131072;
    ushort_t* wTh = (ushort_t*)q;   q += 32768;
    ushort_t* wTl = (ushort_t*)q;
    float* fpr = (float*)d_out;                        // alias d_out (dead before k_proj)
    float* fpi = fpr + 524288;

    k_fill_tw<<<4, 256, 0, stream>>>(ctab, stab);
    k_fill_T1<<<256, 256, 0, stream>>>(T1h, T1l);
    k_fill_T2<<<256, 256, 0, stream>>>(T2h, T2l);
    k_fill_wT<<<dim3(16, 4), 256, 0, stream>>>((const float*)d_in[5], (const float*)d_in[8],
                                               (const float*)d_in[11], (const float*)d_in[14], wTh, wTl);
    k_shallow<<<65536, 256, 0, stream>>>(in, Wsh, bsh, vt);
    if (fused)
        k_f1<<<1024, 256, 0, stream>>>(vt, T1h, T1l, gT);
    for (int L = 0; L < 4; ++L) {
        const float* Rr = (const float*)d_in[3 + L * 3];
        const float* Ri = (const float*)d_in[4 + L * 3];
        if (!fused)
            k_f1<<<1024, 256, 0, stream>>>(vt, T1h, T1l, gT);
        k_f2<<<dim3(8, 16), 256, 0, stream>>>(gT, ctab, stab, fpr, fpi);
        k_mix<<<1024, 64, 0, stream>>>(fpr, fpi, Rr, Ri, Rfr, Rfi);
        k_i1<<<1024, 256, 0, stream>>>(Rfr, Rfi, ctab, stab, Bh, Bl);
        float* gT_next = (fused && L < 3) ? gT : nullptr;
        k_i2f<<<1024, 256, 0, stream>>>(vt, Bh, Bl, T2h, T2l,
                                        wTh + L * 4096, wTl + L * 4096, T1h, T1l, gT_next);
    }
    k_proj<<<4096, 256, 0, stream>>>(vt, Wp, bp, (float*)d_out);
}

// Round 5
// 1749.805 us; speedup vs baseline: 1.3257x; 1.0079x over previous
//
#include <hip/hip_runtime.h>
#include <math.h>

#define MASKN 1023

typedef unsigned short ushort_t;
typedef __attribute__((ext_vector_type(8))) short short8;
typedef __attribute__((ext_vector_type(4))) float floatx4;

__device__ __forceinline__ float gelu_f(float x) {
    return 0.5f * x * (1.0f + erff(x * 0.7071067811865475f));
}

// ---- bf16 storage helpers (compute stays fp32) ----
__device__ __forceinline__ float bf2f(ushort_t h) {
    return __uint_as_float(((unsigned int)h) << 16);
}
__device__ __forceinline__ ushort_t f2bf(float f) {
    unsigned int u = __float_as_uint(f);
    u += 0x7FFFu + ((u >> 16) & 1u);   // round to nearest even
    return (ushort_t)(u >> 16);
}
struct us4 { ushort_t x, y, z, w; };

__device__ __forceinline__ void st4(ushort_t* p, float4 v) {
    us4 h; h.x = f2bf(v.x); h.y = f2bf(v.y); h.z = f2bf(v.z); h.w = f2bf(v.w);
    *(us4*)p = h;
}

// ---------------- twiddle step table for k_f2 / k_i1
__global__ void k_fill_tw(float* __restrict__ ct, float* __restrict__ st) {
    int j = blockIdx.x * 256 + threadIdx.x;   // 0..1023
    float ang = (float)j * (6.283185307179586f / 1024.0f);
    float s, c;
    sincosf(ang, &s, &c);
    ct[j] = c; st[j] = s;
}

// ---------------- T1 table: T1[k2p][y], [2k2][y]=cos(2pi k2 y/1024), [2k2+1][y]=-sin, hi/lo split
__global__ void k_fill_T1(ushort_t* __restrict__ T1h, ushort_t* __restrict__ T1l) {
    int idx = blockIdx.x * 256 + threadIdx.x;   // 0..65535
    int k2p = idx >> 10, y = idx & 1023;
    int k2 = k2p >> 1;
    float ang = (float)((k2 * y) & MASKN) * (6.283185307179586f / 1024.0f);
    float s, c;
    sincosf(ang, &s, &c);
    float v = (k2p & 1) ? -s : c;
    ushort_t h = f2bf(v);
    T1h[idx] = h;
    T1l[idx] = f2bf(v - bf2f(h));
}

// ---------------- T2 table: T2[n2][kk], [n2][2k2]=cos(2pi n2 k2/1024), [n2][2k2+1]=-sin, hi/lo
__global__ void k_fill_T2(ushort_t* __restrict__ T2h, ushort_t* __restrict__ T2l) {
    int idx = blockIdx.x * 256 + threadIdx.x;   // 0..65535
    int n2 = idx >> 6, kk = idx & 63;
    int k2 = kk >> 1;
    float ang = (float)((k2 * n2) & MASKN) * (6.283185307179586f / 1024.0f);
    float s, c;
    sincosf(ang, &s, &c);
    float v = (kk & 1) ? -s : c;
    ushort_t h = f2bf(v);
    T2h[idx] = h;
    T2l[idx] = f2bf(v - bf2f(h));
}

// ---------------- wT tables: wT[l][d][c] = w_l[c][d], hi/lo
__global__ void k_fill_wT(const float* __restrict__ w1, const float* __restrict__ w2,
        const float* __restrict__ w3, const float* __restrict__ w4,
        ushort_t* __restrict__ wTh, ushort_t* __restrict__ wTl) {
    int l = blockIdx.y;
    int i = blockIdx.x * 256 + threadIdx.x;   // 0..4095
    int d = i >> 6, c = i & 63;
    const float* w = (l == 0) ? w1 : (l == 1) ? w2 : (l == 2) ? w3 : w4;
    float v = w[c * 64 + d];
    ushort_t h = f2bf(v);
    wTh[l * 4096 + i] = h;
    wTl[l * 4096 + i] = f2bf(v - bf2f(h));
}

// ---------------- gT zero
__global__ __launch_bounds__(256) void k_gzero(float4* __restrict__ g) {
    g[blockIdx.x * 256 + threadIdx.x] = make_float4(0.f, 0.f, 0.f, 0.f);
}

// ---------------- shallow: vt[p][c] = gelu(in[p][0]*Wsh[0][c] + in[p][1]*Wsh[1][c] + bsh[c])
__global__ __launch_bounds__(256) void k_shallow(const float* __restrict__ in,
        const float* __restrict__ Wsh, const float* __restrict__ bsh,
        ushort_t* __restrict__ vt) {
    int tid = blockIdx.x * 256 + threadIdx.x;
    int p = tid >> 4, c0 = (tid & 15) << 2;
    float a0 = in[p * 2], a1 = in[p * 2 + 1];
    float4 w0 = *(const float4*)&Wsh[c0];
    float4 w1 = *(const float4*)&Wsh[64 + c0];
    float4 b  = *(const float4*)&bsh[c0];
    float4 r;
    r.x = gelu_f(fmaf(a0, w0.x, fmaf(a1, w1.x, b.x)));
    r.y = gelu_f(fmaf(a0, w0.y, fmaf(a1, w1.y, b.y)));
    r.z = gelu_f(fmaf(a0, w0.z, fmaf(a1, w1.z, b.z)));
    r.w = gelu_f(fmaf(a0, w0.w, fmaf(a1, w1.w, b.w)));
    st4(&vt[(size_t)p * 64 + c0], r);
}

// ---------------- F1 (standalone, MFMA): gT[x][c][k2p] = sum_y vt[x][y][c] * T1[k2p][y]
#define F1S 136   // LDS row stride (bf16) for transposed vt tile
__global__ __launch_bounds__(256) void k_f1(const ushort_t* __restrict__ vt,
        const ushort_t* __restrict__ T1h, const ushort_t* __restrict__ T1l,
        float* __restrict__ gT) {
    __shared__ __align__(16) ushort_t vs[64 * F1S];   // 17408 B
    int t = threadIdx.x;
    int x = blockIdx.x;
    int wv = t >> 6, ln = t & 63;
    int lm = ln & 15, quad = ln >> 4;
    int mt = wv;                          // wave's m-tile (16 c rows)
    int lrow = t & 127, chalf = (t >> 7) * 32;   // staging map
    floatx4 acc[4];
    #pragma unroll
    for (int nt = 0; nt < 4; ++nt) acc[nt] = (floatx4)(0.f);
    const ushort_t* vrow = vt + (size_t)x * 65536;
    for (int ch = 0; ch < 8; ++ch) {
        __syncthreads();
        const ushort_t* src = vrow + (size_t)(ch * 128 + lrow) * 64 + chalf;
        #pragma unroll
        for (int i = 0; i < 4; ++i) {
            union { uint4 u; ushort_t e[8]; } uv;
            uv.u = *(const uint4*)(src + i * 8);
            #pragma unroll
            for (int j = 0; j < 8; ++j)
                vs[(chalf + i * 8 + j) * F1S + lrow] = uv.e[j];
        }
        __syncthreads();
        #pragma unroll
        for (int ks = 0; ks < 4; ++ks) {
            short8 af = *(const short8*)&vs[(mt * 16 + lm) * F1S + ks * 32 + quad * 8];
            int ybase = ch * 128 + ks * 32 + quad * 8;
            #pragma unroll
            for (int nt = 0; nt < 4; ++nt) {
                short8 bh = *(const short8*)(T1h + (size_t)(nt * 16 + lm) * 1024 + ybase);
                short8 bl = *(const short8*)(T1l + (size_t)(nt * 16 + lm) * 1024 + ybase);
                acc[nt] = __builtin_amdgcn_mfma_f32_16x16x32_bf16(af, bh, acc[nt], 0, 0, 0);
                acc[nt] = __builtin_amdgcn_mfma_f32_16x16x32_bf16(af, bl, acc[nt], 0, 0, 0);
            }
        }
    }
    float* grow = gT + (size_t)x * 4096;
    #pragma unroll
    for (int nt = 0; nt < 4; ++nt)
        #pragma unroll
        for (int r = 0; r < 4; ++r)
            grow[(mt * 16 + quad * 4 + r) * 64 + nt * 16 + lm] = acc[nt][r];
}

// ---------------- F2: fp[cx][k1*32+k2][c] = sum_{x in cx} g[x][k2][c] (x) e^{-2pi i k1 x/1024}
// grid (8 cx, 16 cg, 4 k1-groups)
__global__ __launch_bounds__(256) void k_f2(const float* __restrict__ gT,
        const float* __restrict__ ct, const float* __restrict__ st,
        float* __restrict__ fpr, float* __restrict__ fpi) {
    int t = threadIdx.x;
    int cx = blockIdx.x;          // 0..7
    int cg = blockIdx.y;          // 0..15
    int k10 = blockIdx.z * 8;     // 0,8,16,24
    int l = t & 63;               // k2p
    int q = t >> 6;               // 0..3
    int c = cg * 4 + q;
    int e = l & 1;                // 0 = re lane, 1 = im lane
    int k2 = l >> 1;
    float acc[8];
    #pragma unroll
    for (int i = 0; i < 8; ++i) acc[i] = 0.f;
    for (int xi = 0; xi < 128; ++xi) {
        int x = cx * 128 + xi;
        float v = gT[(size_t)x * 4096 + c * 64 + l];
        float p = __shfl_xor(v, 1);
        float gr = e ? p : v;
        float gi = e ? v : p;
        float u  = e ? gi : gr;
        float w2 = e ? -gr : gi;
        float cb = ct[x], sb = st[x];
        int ph = (x * k10) & MASKN;
        float cr = ct[ph], sr = st[ph];
        #pragma unroll
        for (int j = 0; j < 8; ++j) {
            acc[j] = fmaf(u, cr, fmaf(w2, sr, acc[j]));
            float nc = fmaf(cr, cb, -sr * sb);
            float ns = fmaf(sr, cb, cr * sb);
            cr = nc; sr = ns;
        }
    }
    float* dst = e ? fpi : fpr;
    #pragma unroll
    for (int j = 0; j < 8; ++j)
        dst[(size_t)cx * 65536 + ((k10 + j) * 32 + k2) * 64 + c] = acc[j];
}

// ---------------- MIX: Rf[m,d] = sum_c f[m,c] * (Rr+iRi)[m,c,d], f = sum of 8 partials
__global__ __launch_bounds__(64) void k_mix(const float* __restrict__ fpr, const float* __restrict__ fpi,
        const float* __restrict__ Rr, const float* __restrict__ Ri,
        float* __restrict__ Rfr, float* __restrict__ Rfi) {
    __shared__ float fr[64], fi[64];
    int m = blockIdx.x;
    int d = threadIdx.x;
    float sr = 0.f, si = 0.f;
    #pragma unroll
    for (int ch = 0; ch < 8; ++ch) {
        sr += fpr[(size_t)ch * 65536 + m * 64 + d];
        si += fpi[(size_t)ch * 65536 + m * 64 + d];
    }
    fr[d] = sr; fi[d] = si;
    __syncthreads();
    const float* Rrb = Rr + (size_t)m * 4096;
    const float* Rib = Ri + (size_t)m * 4096;
    float ar = 0.f, ai = 0.f;
    for (int c = 0; c < 64; ++c) {
        float rr = Rrb[c * 64 + d], ri = Rib[c * 64 + d];
        ar = fmaf(fr[c], rr, fmaf(-fi[c], ri, ar));
        ai = fmaf(fr[c], ri, fmaf(fi[c], rr, ai));
    }
    Rfr[m * 64 + d] = ar;
    Rfi[m * 64 + d] = ai;
}

// ---------------- I1: Bmat[n1][d][kk] (bf16 hi/lo, kk = 2k2(+1) = re/im interleaved)
__global__ __launch_bounds__(256) void k_i1(const float* __restrict__ Rfr, const float* __restrict__ Rfi,
        const float* __restrict__ ctg, const float* __restrict__ stg,
        ushort_t* __restrict__ Bh, ushort_t* __restrict__ Bl) {
    __shared__ float ct[1024], st[1024];
    int t = threadIdx.x;
    #pragma unroll
    for (int i = 0; i < 4; ++i) { int j = t + 256 * i; ct[j] = ctg[j]; st[j] = stg[j]; }
    __syncthreads();
    int n1 = blockIdx.x;
    int d = t & 63;
    int k20 = (t >> 6) * 8;
    float br[8], bi[8];
    #pragma unroll
    for (int j = 0; j < 8; ++j) { br[j] = 0.f; bi[j] = 0.f; }
    int idx = 0;
    for (int k1 = 0; k1 < 32; ++k1) {
        float cc = ct[idx], ss = st[idx];
        idx = (idx + n1) & MASKN;
        #pragma unroll
        for (int j = 0; j < 8; ++j) {
            float rr = Rfr[(k1 * 32 + k20 + j) * 64 + d];
            float ri = Rfi[(k1 * 32 + k20 + j) * 64 + d];
            br[j] = fmaf(rr, cc, fmaf(-ri, ss, br[j]));
            bi[j] = fmaf(rr, ss, fmaf(ri, cc, bi[j]));
        }
    }
    union { uint4 u[2]; ushort_t e[16]; } hh, ll;
    #pragma unroll
    for (int j = 0; j < 8; ++j) {
        int k2 = k20 + j;
        float sc = (k2 == 0 ? 1.0f : 2.0f) * 9.5367431640625e-7f;   // 1/2^20
        float vr = br[j] * sc, vi = bi[j] * sc;
        ushort_t hr = f2bf(vr), hi2 = f2bf(vi);
        hh.e[2 * j] = hr;          hh.e[2 * j + 1] = hi2;
        ll.e[2 * j] = f2bf(vr - bf2f(hr));
        ll.e[2 * j + 1] = f2bf(vi - bf2f(hi2));
    }
    size_t base = ((size_t)n1 * 64 + d) * 64 + 2 * k20;
    *(uint4*)(Bh + base) = hh.u[0];
    *(uint4*)(Bh + base + 8) = hh.u[1];
    *(uint4*)(Bl + base) = ll.u[0];
    *(uint4*)(Bl + base + 8) = ll.u[1];
}

// ---------------- I2 fused with next layer's F1 partial.
// grid (1024 n1, 2 n2-halves); 4 chunks of 128 n2 per block. Per chunk:
// MFMA i2 (T2@B + vt@w) with vt A-frags prefetched one chunk ahead; gelu
// epilogue -> global vt + packed transposed LDS tile; barrier; accumulate
// gacc += vs[c][y] @ T1[k2p][y]; at end atomicAdd gacc into gT (2 partials).
#define I2S 136
__global__ __launch_bounds__(256) void k_i2f(ushort_t* __restrict__ vt,
        const ushort_t* __restrict__ Bh, const ushort_t* __restrict__ Bl,
        const ushort_t* __restrict__ T2h, const ushort_t* __restrict__ T2l,
        const ushort_t* __restrict__ wTh, const ushort_t* __restrict__ wTl,
        const ushort_t* __restrict__ T1h, const ushort_t* __restrict__ T1l,
        float* __restrict__ gT) {
    __shared__ __align__(16) ushort_t vs[2][64 * I2S];   // 2 x 17408 B
    int t = threadIdx.x;
    int wv = t >> 6, ln = t & 63;
    int lm = ln & 15, quad = ln >> 4;
    int n1 = blockIdx.x;
    int h = blockIdx.y;                 // n2 half
    const ushort_t* Bhr = Bh + (size_t)n1 * 4096;
    const ushort_t* Blr = Bl + (size_t)n1 * 4096;
    bool dof1 = (gT != nullptr);
    floatx4 gacc[4];
    #pragma unroll
    for (int nt = 0; nt < 4; ++nt) gacc[nt] = (floatx4)(0.f);

    ushort_t* vbase = vt + ((size_t)n1 * 1024 + h * 512) * 64;
    // prefetch chunk 0's skip A-frags (wave-private rows -> race-free)
    short8 pa0[2], pa1[2];
    {
        const ushort_t* vr = vbase + (size_t)(wv * 32) * 64;
        #pragma unroll
        for (int ks = 0; ks < 2; ++ks) {
            pa0[ks] = *(const short8*)(vr + (size_t)lm * 64 + ks * 32 + quad * 8);
            pa1[ks] = *(const short8*)(vr + (size_t)(16 + lm) * 64 + ks * 32 + quad * 8);
        }
    }

    for (int ch = 0; ch < 4; ++ch) {
        int n2b = h * 512 + ch * 128 + wv * 32;
        ushort_t* vrow = vbase + (size_t)(ch * 128 + wv * 32) * 64;
        floatx4 acc[2][4];
        #pragma unroll
        for (int m = 0; m < 2; ++m)
            #pragma unroll
            for (int nt = 0; nt < 4; ++nt) acc[m][nt] = (floatx4)(0.f);
        // phase 1: T2 x Bmat  (hi*hi + lo*hi + hi*lo)
        #pragma unroll
        for (int ks = 0; ks < 2; ++ks) {
            int kk = ks * 32 + quad * 8;
            short8 a0h = *(const short8*)(T2h + (size_t)(n2b + lm) * 64 + kk);
            short8 a1h = *(const short8*)(T2h + (size_t)(n2b + 16 + lm) * 64 + kk);
            short8 a0l = *(const short8*)(T2l + (size_t)(n2b + lm) * 64 + kk);
            short8 a1l = *(const short8*)(T2l + (size_t)(n2b + 16 + lm) * 64 + kk);
            #pragma unroll
            for (int nt = 0; nt < 4; ++nt) {
                short8 bh = *(const short8*)(Bhr + (nt * 16 + lm) * 64 + kk);
                short8 bl = *(const short8*)(Blr + (nt * 16 + lm) * 64 + kk);
                acc[0][nt] = __builtin_amdgcn_mfma_f32_16x16x32_bf16(a0h, bh, acc[0][nt], 0, 0, 0);
                acc[1][nt] = __builtin_amdgcn_mfma_f32_16x16x32_bf16(a1h, bh, acc[1][nt], 0, 0, 0);
                acc[0][nt] = __builtin_amdgcn_mfma_f32_16x16x32_bf16(a0l, bh, acc[0][nt], 0, 0, 0);
                acc[1][nt] = __builtin_amdgcn_mfma_f32_16x16x32_bf16(a1l, bh, acc[1][nt], 0, 0, 0);
                acc[0][nt] = __builtin_amdgcn_mfma_f32_16x16x32_bf16(a0h, bl, acc[0][nt], 0, 0, 0);
                acc[1][nt] = __builtin_amdgcn_mfma_f32_16x16x32_bf16(a1h, bl, acc[1][nt], 0, 0, 0);
            }
        }
        // phase 2: vt x w  (prefetched A-frags)
        #pragma unroll
        for (int ks = 0; ks < 2; ++ks) {
            int cc = ks * 32 + quad * 8;
            #pragma unroll
            for (int nt = 0; nt < 4; ++nt) {
                short8 bh = *(const short8*)(wTh + (nt * 16 + lm) * 64 + cc);
                short8 bl = *(const short8*)(wTl + (nt * 16 + lm) * 64 + cc);
                acc[0][nt] = __builtin_amdgcn_mfma_f32_16x16x32_bf16(pa0[ks], bh, acc[0][nt], 0, 0, 0);
                acc[1][nt] = __builtin_amdgcn_mfma_f32_16x16x32_bf16(pa1[ks], bh, acc[1][nt], 0, 0, 0);
                acc[0][nt] = __builtin_amdgcn_mfma_f32_16x16x32_bf16(pa0[ks], bl, acc[0][nt], 0, 0, 0);
                acc[1][nt] = __builtin_amdgcn_mfma_f32_16x16x32_bf16(pa1[ks], bl, acc[1][nt], 0, 0, 0);
            }
        }
        // prefetch next chunk's skip A-frags (hidden behind epilogue+barrier+f1)
        if (ch < 3) {
            const ushort_t* vr = vbase + (size_t)((ch + 1) * 128 + wv * 32) * 64;
            #pragma unroll
            for (int ks = 0; ks < 2; ++ks) {
                pa0[ks] = *(const short8*)(vr + (size_t)lm * 64 + ks * 32 + quad * 8);
                pa1[ks] = *(const short8*)(vr + (size_t)(16 + lm) * 64 + ks * 32 + quad * 8);
            }
        }
        // epilogue: gelu + bf16 store to global + packed transposed LDS tile
        ushort_t* vsb = vs[ch & 1];
        #pragma unroll
        for (int m = 0; m < 2; ++m)
            #pragma unroll
            for (int nt = 0; nt < 4; ++nt) {
                union { ushort_t e[4]; uint2 u; } pk;
                #pragma unroll
                for (int r = 0; r < 4; ++r) {
                    ushort_t hv = f2bf(gelu_f(acc[m][nt][r]));
                    pk.e[r] = hv;
                    vrow[(size_t)(m * 16 + quad * 4 + r) * 64 + nt * 16 + lm] = hv;
                }
                if (dof1)
                    *(uint2*)&vsb[(nt * 16 + lm) * I2S + wv * 32 + m * 16 + quad * 4] = pk.u;
            }
        __syncthreads();
        if (dof1) {
            #pragma unroll
            for (int ks = 0; ks < 4; ++ks) {
                short8 af = *(const short8*)&vsb[(wv * 16 + lm) * I2S + ks * 32 + quad * 8];
                int ybase = h * 512 + ch * 128 + ks * 32 + quad * 8;
                #pragma unroll
                for (int nt = 0; nt < 4; ++nt) {
                    short8 bh = *(const short8*)(T1h + (size_t)(nt * 16 + lm) * 1024 + ybase);
                    short8 bl = *(const short8*)(T1l + (size_t)(nt * 16 + lm) * 1024 + ybase);
                    gacc[nt] = __builtin_amdgcn_mfma_f32_16x16x32_bf16(af, bh, gacc[nt], 0, 0, 0);
                    gacc[nt] = __builtin_amdgcn_mfma_f32_16x16x32_bf16(af, bl, gacc[nt], 0, 0, 0);
                }
            }
        }
    }
    if (dof1) {
        float* grow = gT + (size_t)n1 * 4096;
        #pragma unroll
        for (int nt = 0; nt < 4; ++nt)
            #pragma unroll
            for (int r = 0; r < 4; ++r)
                atomicAdd(&grow[(wv * 16 + quad * 4 + r) * 64 + nt * 16 + lm], gacc[nt][r]);
    }
}

// ---------------- projection: out[p] = sum_c vt[p,c]*Wp[c] + bp[0]
__global__ __launch_bounds__(256) void k_proj(const ushort_t* __restrict__ vt,
        const float* __restrict__ Wp, const float* __restrict__ bp,
        float* __restrict__ out) {
    __shared__ float wp[64];
    int t = threadIdx.x;
    if (t < 64) wp[t] = Wp[t];
    __syncthreads();
    int p = blockIdx.x * 256 + t;
    const ushort_t* v = vt + (size_t)p * 64;
    float acc = bp[0];
    #pragma unroll
    for (int i = 0; i < 16; ++i) {
        us4 a = *(const us4*)&v[i * 4];
        acc = fmaf(bf2f(a.x), wp[i * 4 + 0], acc);
        acc = fmaf(bf2f(a.y), wp[i * 4 + 1], acc);
        acc = fmaf(bf2f(a.z), wp[i * 4 + 2], acc);
        acc = fmaf(bf2f(a.w), wp[i * 4 + 3], acc);
    }
    out[p] = acc;
}

extern "C" void kernel_launch(void* const* d_in, const int* in_sizes, int n_in,
                              void* d_out, int out_size, void* d_ws, size_t ws_size,
                              hipStream_t stream) {
    const float* in  = (const float*)d_in[0];
    const float* Wsh = (const float*)d_in[1];
    const float* bsh = (const float*)d_in[2];
    const float* Wp  = (const float*)d_in[15];
    const float* bp  = (const float*)d_in[16];

    // ---- workspace layout ----
    char* wsb = (char*)d_ws;
    ushort_t* vt = (ushort_t*)wsb;                     // 134,217,728 B
    char* p = wsb + 134217728;
    float* gT = (float*)p;          p += 16777216;     // 1024*64*64 f32
    char* bregion_fused = p;                           // +16,777,216 if fused
    const size_t TAIL = 524288 + 8192 + 262144 + 262144 + 65536;  // Rf + tw + T1 + T2 + wT
    const size_t NEED_FUSED = 134217728ull + 16777216ull + 16777216ull + TAIL;
    bool fused = (ws_size >= NEED_FUSED);

    ushort_t *Bh, *Bl;
    char* q;
    if (fused) {
        Bh = (ushort_t*)bregion_fused;                 // separate 16 MB
        Bl = Bh + 4194304;
        q = bregion_fused + 16777216;
    } else {
        Bh = (ushort_t*)gT;                            // alias gT (dead after k_f2)
        Bl = Bh + 4194304;
        q = bregion_fused;
    }
    float* Rfr  = (float*)q;        q += 262144;
    float* Rfi  = (float*)q;        q += 262144;
    float* ctab = (float*)q;        q += 4096;
    float* stab = (float*)q;        q += 4096;
    ushort_t* T1h = (ushort_t*)q;   q += 131072;
    ushort_t* T1l = (ushort_t*)q;   q += 131072;
    ushort_t* T2h = (ushort_t*)q;   q += 131072;
    ushort_t* T2l = (ushort_t*)q;   q += 131072;
    ushort_t* wTh = (ushort_t*)q;   q += 32768;
    ushort_t* wTl = (ushort_t*)q;
    float* fpr = (float*)d_out;                        // alias d_out (dead before k_proj)
    float* fpi = fpr + 524288;

    k_fill_tw<<<4, 256, 0, stream>>>(ctab, stab);
    k_fill_T1<<<256, 256, 0, stream>>>(T1h, T1l);
    k_fill_T2<<<256, 256, 0, stream>>>(T2h, T2l);
    k_fill_wT<<<dim3(16, 4), 256, 0, stream>>>((const float*)d_in[5], (const float*)d_in[8],
                                               (const float*)d_in[11], (const float*)d_in[14], wTh, wTl);
    k_shallow<<<65536, 256, 0, stream>>>(in, Wsh, bsh, vt);
    if (fused)
        k_f1<<<1024, 256, 0, stream>>>(vt, T1h, T1l, gT);
    for (int L = 0; L < 4; ++L) {
        const float* Rr = (const float*)d_in[3 + L * 3];
        const float* Ri = (const float*)d_in[4 + L * 3];
        if (!fused)
            k_f1<<<1024, 256, 0, stream>>>(vt, T1h, T1l, gT);
        k_f2<<<dim3(8, 16, 4), 256, 0, stream>>>(gT, ctab, stab, fpr, fpi);
        if (fused && L < 3)
            k_gzero<<<4096, 256, 0, stream>>>((float4*)gT);
        k_mix<<<1024, 64, 0, stream>>>(fpr, fpi, Rr, Ri, Rfr, Rfi);
        k_i1<<<1024, 256, 0, stream>>>(Rfr, Rfi, ctab, stab, Bh, Bl);
        float* gT_next = (fused && L < 3) ? gT : nullptr;
        k_i2f<<<dim3(1024, 2), 256, 0, stream>>>(vt, Bh, Bl, T2h, T2l,
                                                 wTh + L * 4096, wTl + L * 4096, T1h, T1l, gT_next);
    }
    k_proj<<<4096, 256, 0, stream>>>(vt, Wp, bp, (float*)d_out);
}

// Round 6
// 1687.132 us; speedup vs baseline: 1.3749x; 1.0371x over previous
//
#include <hip/hip_runtime.h>
#include <math.h>

#define MASKN 1023

typedef unsigned short ushort_t;
typedef __attribute__((ext_vector_type(8))) short short8;
typedef __attribute__((ext_vector_type(4))) float floatx4;

// tanh-form GELU as x * sigmoid(2*0.7978845608*(x + 0.044715 x^3)); one v_exp_f32.
// max |diff| vs exact erf-gelu ~3e-4, far under the bf16 noise already present.
__device__ __forceinline__ float gelu_f(float x) {
    float x2 = x * x;
    float inner = fmaf(0.044715f * x, x2, x);
    float t = exp2f(inner * -2.302089214f);   // 2^(-2*0.7978845608*log2(e)*inner)
    return x / (1.0f + t);
}

// ---- bf16 storage helpers (compute stays fp32) ----
__device__ __forceinline__ float bf2f(ushort_t h) {
    return __uint_as_float(((unsigned int)h) << 16);
}
__device__ __forceinline__ ushort_t f2bf(float f) {
    unsigned int u = __float_as_uint(f);
    u += 0x7FFFu + ((u >> 16) & 1u);   // round to nearest even
    return (ushort_t)(u >> 16);
}
struct us4 { ushort_t x, y, z, w; };

__device__ __forceinline__ void st4(ushort_t* p, float4 v) {
    us4 h; h.x = f2bf(v.x); h.y = f2bf(v.y); h.z = f2bf(v.z); h.w = f2bf(v.w);
    *(us4*)p = h;
}

// ---------------- twiddle step table for k_f2 / k_i1
__global__ void k_fill_tw(float* __restrict__ ct, float* __restrict__ st) {
    int j = blockIdx.x * 256 + threadIdx.x;   // 0..1023
    float ang = (float)j * (6.283185307179586f / 1024.0f);
    float s, c;
    sincosf(ang, &s, &c);
    ct[j] = c; st[j] = s;
}

// ---------------- T1 table: T1[k2p][y], [2k2][y]=cos(2pi k2 y/1024), [2k2+1][y]=-sin, hi/lo split
__global__ void k_fill_T1(ushort_t* __restrict__ T1h, ushort_t* __restrict__ T1l) {
    int idx = blockIdx.x * 256 + threadIdx.x;   // 0..65535
    int k2p = idx >> 10, y = idx & 1023;
    int k2 = k2p >> 1;
    float ang = (float)((k2 * y) & MASKN) * (6.283185307179586f / 1024.0f);
    float s, c;
    sincosf(ang, &s, &c);
    float v = (k2p & 1) ? -s : c;
    ushort_t h = f2bf(v);
    T1h[idx] = h;
    T1l[idx] = f2bf(v - bf2f(h));
}

// ---------------- T2 table: T2[n2][kk], [n2][2k2]=cos(2pi n2 k2/1024), [n2][2k2+1]=-sin, hi/lo
__global__ void k_fill_T2(ushort_t* __restrict__ T2h, ushort_t* __restrict__ T2l) {
    int idx = blockIdx.x * 256 + threadIdx.x;   // 0..65535
    int n2 = idx >> 6, kk = idx & 63;
    int k2 = kk >> 1;
    float ang = (float)((k2 * n2) & MASKN) * (6.283185307179586f / 1024.0f);
    float s, c;
    sincosf(ang, &s, &c);
    float v = (kk & 1) ? -s : c;
    ushort_t h = f2bf(v);
    T2h[idx] = h;
    T2l[idx] = f2bf(v - bf2f(h));
}

// ---------------- wT tables: wT[l][d][c] = w_l[c][d], hi/lo
__global__ void k_fill_wT(const float* __restrict__ w1, const float* __restrict__ w2,
        const float* __restrict__ w3, const float* __restrict__ w4,
        ushort_t* __restrict__ wTh, ushort_t* __restrict__ wTl) {
    int l = blockIdx.y;
    int i = blockIdx.x * 256 + threadIdx.x;   // 0..4095
    int d = i >> 6, c = i & 63;
    const float* w = (l == 0) ? w1 : (l == 1) ? w2 : (l == 2) ? w3 : w4;
    float v = w[c * 64 + d];
    ushort_t h = f2bf(v);
    wTh[l * 4096 + i] = h;
    wTl[l * 4096 + i] = f2bf(v - bf2f(h));
}

// ---------------- shallow: vt[p][c] = gelu(in[p][0]*Wsh[0][c] + in[p][1]*Wsh[1][c] + bsh[c])
__global__ __launch_bounds__(256) void k_shallow(const float* __restrict__ in,
        const float* __restrict__ Wsh, const float* __restrict__ bsh,
        ushort_t* __restrict__ vt) {
    int tid = blockIdx.x * 256 + threadIdx.x;
    int p = tid >> 4, c0 = (tid & 15) << 2;
    float a0 = in[p * 2], a1 = in[p * 2 + 1];
    float4 w0 = *(const float4*)&Wsh[c0];
    float4 w1 = *(const float4*)&Wsh[64 + c0];
    float4 b  = *(const float4*)&bsh[c0];
    float4 r;
    r.x = gelu_f(fmaf(a0, w0.x, fmaf(a1, w1.x, b.x)));
    r.y = gelu_f(fmaf(a0, w0.y, fmaf(a1, w1.y, b.y)));
    r.z = gelu_f(fmaf(a0, w0.z, fmaf(a1, w1.z, b.z)));
    r.w = gelu_f(fmaf(a0, w0.w, fmaf(a1, w1.w, b.w)));
    st4(&vt[(size_t)p * 64 + c0], r);
}

// ---------------- F1 (MFMA): gT[x][c][k2p] = sum_y vt[x][y][c] * T1[k2p][y]
// block = one x; double-buffered LDS transpose, register prefetch of next chunk,
// single barrier per chunk.
#define F1S 136   // LDS row stride (bf16) for transposed vt tile
__global__ __launch_bounds__(256) void k_f1(const ushort_t* __restrict__ vt,
        const ushort_t* __restrict__ T1h, const ushort_t* __restrict__ T1l,
        float* __restrict__ gT) {
    __shared__ __align__(16) ushort_t vs[2][64 * F1S];   // 2 x 17408 B
    int t = threadIdx.x;
    int x = blockIdx.x;
    int wv = t >> 6, ln = t & 63;
    int lm = ln & 15, quad = ln >> 4;
    int mt = wv;                          // wave's m-tile (16 c rows)
    int lrow = t & 127, chalf = (t >> 7) * 32;   // staging map
    floatx4 acc[4];
    #pragma unroll
    for (int nt = 0; nt < 4; ++nt) acc[nt] = (floatx4)(0.f);
    const ushort_t* vrow = vt + (size_t)x * 65536;
    uint4 pf[4];
    {
        const ushort_t* src = vrow + (size_t)lrow * 64 + chalf;
        #pragma unroll
        for (int i = 0; i < 4; ++i) pf[i] = *(const uint4*)(src + i * 8);
    }
    for (int ch = 0; ch < 8; ++ch) {
        ushort_t* vsb = vs[ch & 1];
        // scatter staged registers transposed into LDS: vs[c][y]
        #pragma unroll
        for (int i = 0; i < 4; ++i) {
            union { uint4 u; ushort_t e[8]; } uv;
            uv.u = pf[i];
            #pragma unroll
            for (int j = 0; j < 8; ++j)
                vsb[(chalf + i * 8 + j) * F1S + lrow] = uv.e[j];
        }
        // prefetch next chunk (overlaps barrier + MFMA below)
        if (ch < 7) {
            const ushort_t* src = vrow + (size_t)((ch + 1) * 128 + lrow) * 64 + chalf;
            #pragma unroll
            for (int i = 0; i < 4; ++i) pf[i] = *(const uint4*)(src + i * 8);
        }
        __syncthreads();
        #pragma unroll
        for (int ks = 0; ks < 4; ++ks) {
            short8 af = *(const short8*)&vsb[(mt * 16 + lm) * F1S + ks * 32 + quad * 8];
            int ybase = ch * 128 + ks * 32 + quad * 8;
            #pragma unroll
            for (int nt = 0; nt < 4; ++nt) {
                short8 bh = *(const short8*)(T1h + (size_t)(nt * 16 + lm) * 1024 + ybase);
                short8 bl = *(const short8*)(T1l + (size_t)(nt * 16 + lm) * 1024 + ybase);
                acc[nt] = __builtin_amdgcn_mfma_f32_16x16x32_bf16(af, bh, acc[nt], 0, 0, 0);
                acc[nt] = __builtin_amdgcn_mfma_f32_16x16x32_bf16(af, bl, acc[nt], 0, 0, 0);
            }
        }
    }
    float* grow = gT + (size_t)x * 4096;
    #pragma unroll
    for (int nt = 0; nt < 4; ++nt)
        #pragma unroll
        for (int r = 0; r < 4; ++r)
            grow[(mt * 16 + quad * 4 + r) * 64 + nt * 16 + lm] = acc[nt][r];
}

// ---------------- F2: fp[cx][k1*32+k2][c] = sum_{x in cx} g[x][k2][c] (x) e^{-2pi i k1 x/1024}
// grid (8 cx, 16 cg, 4 k1-groups)
__global__ __launch_bounds__(256) void k_f2(const float* __restrict__ gT,
        const float* __restrict__ ct, const float* __restrict__ st,
        float* __restrict__ fpr, float* __restrict__ fpi) {
    int t = threadIdx.x;
    int cx = blockIdx.x;          // 0..7
    int cg = blockIdx.y;          // 0..15
    int k10 = blockIdx.z * 8;     // 0,8,16,24
    int l = t & 63;               // k2p
    int q = t >> 6;               // 0..3
    int c = cg * 4 + q;
    int e = l & 1;                // 0 = re lane, 1 = im lane
    int k2 = l >> 1;
    float acc[8];
    #pragma unroll
    for (int i = 0; i < 8; ++i) acc[i] = 0.f;
    for (int xi = 0; xi < 128; ++xi) {
        int x = cx * 128 + xi;
        float v = gT[(size_t)x * 4096 + c * 64 + l];
        float p = __shfl_xor(v, 1);
        float gr = e ? p : v;
        float gi = e ? v : p;
        float u  = e ? gi : gr;
        float w2 = e ? -gr : gi;
        float cb = ct[x], sb = st[x];
        int ph = (x * k10) & MASKN;
        float cr = ct[ph], sr = st[ph];
        #pragma unroll
        for (int j = 0; j < 8; ++j) {
            acc[j] = fmaf(u, cr, fmaf(w2, sr, acc[j]));
            float nc = fmaf(cr, cb, -sr * sb);
            float ns = fmaf(sr, cb, cr * sb);
            cr = nc; sr = ns;
        }
    }
    float* dst = e ? fpi : fpr;
    #pragma unroll
    for (int j = 0; j < 8; ++j)
        dst[(size_t)cx * 65536 + ((k10 + j) * 32 + k2) * 64 + c] = acc[j];
}

// ---------------- MIX: Rf[m,d] = sum_c f[m,c] * (Rr+iRi)[m,c,d], f = sum of 8 partials
__global__ __launch_bounds__(64) void k_mix(const float* __restrict__ fpr, const float* __restrict__ fpi,
        const float* __restrict__ Rr, const float* __restrict__ Ri,
        float* __restrict__ Rfr, float* __restrict__ Rfi) {
    __shared__ float fr[64], fi[64];
    int m = blockIdx.x;
    int d = threadIdx.x;
    float sr = 0.f, si = 0.f;
    #pragma unroll
    for (int ch = 0; ch < 8; ++ch) {
        sr += fpr[(size_t)ch * 65536 + m * 64 + d];
        si += fpi[(size_t)ch * 65536 + m * 64 + d];
    }
    fr[d] = sr; fi[d] = si;
    __syncthreads();
    const float* Rrb = Rr + (size_t)m * 4096;
    const float* Rib = Ri + (size_t)m * 4096;
    float ar = 0.f, ai = 0.f;
    for (int c = 0; c < 64; ++c) {
        float rr = Rrb[c * 64 + d], ri = Rib[c * 64 + d];
        ar = fmaf(fr[c], rr, fmaf(-fi[c], ri, ar));
        ai = fmaf(fr[c], ri, fmaf(fi[c], rr, ai));
    }
    Rfr[m * 64 + d] = ar;
    Rfi[m * 64 + d] = ai;
}

// ---------------- I1: Bmat[n1][d][kk] (bf16 hi/lo, kk = 2k2(+1) = re/im interleaved)
__global__ __launch_bounds__(256) void k_i1(const float* __restrict__ Rfr, const float* __restrict__ Rfi,
        const float* __restrict__ ctg, const float* __restrict__ stg,
        ushort_t* __restrict__ Bh, ushort_t* __restrict__ Bl) {
    __shared__ float ct[1024], st[1024];
    int t = threadIdx.x;
    #pragma unroll
    for (int i = 0; i < 4; ++i) { int j = t + 256 * i; ct[j] = ctg[j]; st[j] = stg[j]; }
    __syncthreads();
    int n1 = blockIdx.x;
    int d = t & 63;
    int k20 = (t >> 6) * 8;
    float br[8], bi[8];
    #pragma unroll
    for (int j = 0; j < 8; ++j) { br[j] = 0.f; bi[j] = 0.f; }
    int idx = 0;
    for (int k1 = 0; k1 < 32; ++k1) {
        float cc = ct[idx], ss = st[idx];
        idx = (idx + n1) & MASKN;
        #pragma unroll
        for (int j = 0; j < 8; ++j) {
            float rr = Rfr[(k1 * 32 + k20 + j) * 64 + d];
            float ri = Rfi[(k1 * 32 + k20 + j) * 64 + d];
            br[j] = fmaf(rr, cc, fmaf(-ri, ss, br[j]));
            bi[j] = fmaf(rr, ss, fmaf(ri, cc, bi[j]));
        }
    }
    union { uint4 u[2]; ushort_t e[16]; } hh, ll;
    #pragma unroll
    for (int j = 0; j < 8; ++j) {
        int k2 = k20 + j;
        float sc = (k2 == 0 ? 1.0f : 2.0f) * 9.5367431640625e-7f;   // 1/2^20
        float vr = br[j] * sc, vi = bi[j] * sc;
        ushort_t hr = f2bf(vr), hi2 = f2bf(vi);
        hh.e[2 * j] = hr;          hh.e[2 * j + 1] = hi2;
        ll.e[2 * j] = f2bf(vr - bf2f(hr));
        ll.e[2 * j + 1] = f2bf(vi - bf2f(hi2));
    }
    size_t base = ((size_t)n1 * 64 + d) * 64 + 2 * k20;
    *(uint4*)(Bh + base) = hh.u[0];
    *(uint4*)(Bh + base + 8) = hh.u[1];
    *(uint4*)(Bl + base) = ll.u[0];
    *(uint4*)(Bl + base + 8) = ll.u[1];
}

// ---------------- I2 (MFMA, fused skip+inverse): vt[n1][n2][d] = gelu( T2[n2,:]@Bmat[n1][:, d] + vt[n1][n2,:]@w[:,d] )
// grid (8 n2-chunks, 1024 n1); 4 waves; wave = 32 n2 x 64 d; no LDS, no barriers. VGPR ~60.
__global__ __launch_bounds__(256) void k_i2(ushort_t* __restrict__ vt,
        const ushort_t* __restrict__ Bh, const ushort_t* __restrict__ Bl,
        const ushort_t* __restrict__ T2h, const ushort_t* __restrict__ T2l,
        const ushort_t* __restrict__ wTh, const ushort_t* __restrict__ wTl) {
    int t = threadIdx.x;
    int wv = t >> 6, ln = t & 63;
    int lm = ln & 15, quad = ln >> 4;
    int chunk = blockIdx.x, n1 = blockIdx.y;
    int n2b = chunk * 128 + wv * 32;
    const ushort_t* Bhr = Bh + (size_t)n1 * 4096;
    const ushort_t* Blr = Bl + (size_t)n1 * 4096;
    ushort_t* vrow = vt + ((size_t)n1 * 1024 + n2b) * 64;
    floatx4 acc[2][4];
    #pragma unroll
    for (int m = 0; m < 2; ++m)
        #pragma unroll
        for (int nt = 0; nt < 4; ++nt) acc[m][nt] = (floatx4)(0.f);
    // phase 1: T2 x Bmat  (hi*hi + lo*hi + hi*lo)
    #pragma unroll
    for (int ks = 0; ks < 2; ++ks) {
        int kk = ks * 32 + quad * 8;
        short8 a0h = *(const short8*)(T2h + (size_t)(n2b + lm) * 64 + kk);
        short8 a1h = *(const short8*)(T2h + (size_t)(n2b + 16 + lm) * 64 + kk);
        short8 a0l = *(const short8*)(T2l + (size_t)(n2b + lm) * 64 + kk);
        short8 a1l = *(const short8*)(T2l + (size_t)(n2b + 16 + lm) * 64 + kk);
        #pragma unroll
        for (int nt = 0; nt < 4; ++nt) {
            short8 bh = *(const short8*)(Bhr + (nt * 16 + lm) * 64 + kk);
            short8 bl = *(const short8*)(Blr + (nt * 16 + lm) * 64 + kk);
            acc[0][nt] = __builtin_amdgcn_mfma_f32_16x16x32_bf16(a0h, bh, acc[0][nt], 0, 0, 0);
            acc[1][nt] = __builtin_amdgcn_mfma_f32_16x16x32_bf16(a1h, bh, acc[1][nt], 0, 0, 0);
            acc[0][nt] = __builtin_amdgcn_mfma_f32_16x16x32_bf16(a0l, bh, acc[0][nt], 0, 0, 0);
            acc[1][nt] = __builtin_amdgcn_mfma_f32_16x16x32_bf16(a1l, bh, acc[1][nt], 0, 0, 0);
            acc[0][nt] = __builtin_amdgcn_mfma_f32_16x16x32_bf16(a0h, bl, acc[0][nt], 0, 0, 0);
            acc[1][nt] = __builtin_amdgcn_mfma_f32_16x16x32_bf16(a1h, bl, acc[1][nt], 0, 0, 0);
        }
    }
    // phase 2: vt x w  (vt * (wh + wl))
    #pragma unroll
    for (int ks = 0; ks < 2; ++ks) {
        int cc = ks * 32 + quad * 8;
        short8 a0 = *(const short8*)(vrow + (size_t)lm * 64 + cc);
        short8 a1 = *(const short8*)(vrow + (size_t)(16 + lm) * 64 + cc);
        #pragma unroll
        for (int nt = 0; nt < 4; ++nt) {
            short8 bh = *(const short8*)(wTh + (nt * 16 + lm) * 64 + cc);
            short8 bl = *(const short8*)(wTl + (nt * 16 + lm) * 64 + cc);
            acc[0][nt] = __builtin_amdgcn_mfma_f32_16x16x32_bf16(a0, bh, acc[0][nt], 0, 0, 0);
            acc[1][nt] = __builtin_amdgcn_mfma_f32_16x16x32_bf16(a1, bh, acc[1][nt], 0, 0, 0);
            acc[0][nt] = __builtin_amdgcn_mfma_f32_16x16x32_bf16(a0, bl, acc[0][nt], 0, 0, 0);
            acc[1][nt] = __builtin_amdgcn_mfma_f32_16x16x32_bf16(a1, bl, acc[1][nt], 0, 0, 0);
        }
    }
    // epilogue: gelu + bf16 store; row = m*16 + quad*4 + r, col d = nt*16 + lm
    #pragma unroll
    for (int m = 0; m < 2; ++m)
        #pragma unroll
        for (int nt = 0; nt < 4; ++nt)
            #pragma unroll
            for (int r = 0; r < 4; ++r)
                vrow[(size_t)(m * 16 + quad * 4 + r) * 64 + nt * 16 + lm] = f2bf(gelu_f(acc[m][nt][r]));
}

// ---------------- projection: out[p] = sum_c vt[p,c]*Wp[c] + bp[0]
__global__ __launch_bounds__(256) void k_proj(const ushort_t* __restrict__ vt,
        const float* __restrict__ Wp, const float* __restrict__ bp,
        float* __restrict__ out) {
    __shared__ float wp[64];
    int t = threadIdx.x;
    if (t < 64) wp[t] = Wp[t];
    __syncthreads();
    int p = blockIdx.x * 256 + t;
    const ushort_t* v = vt + (size_t)p * 64;
    float acc = bp[0];
    #pragma unroll
    for (int i = 0; i < 16; ++i) {
        us4 a = *(const us4*)&v[i * 4];
        acc = fmaf(bf2f(a.x), wp[i * 4 + 0], acc);
        acc = fmaf(bf2f(a.y), wp[i * 4 + 1], acc);
        acc = fmaf(bf2f(a.z), wp[i * 4 + 2], acc);
        acc = fmaf(bf2f(a.w), wp[i * 4 + 3], acc);
    }
    out[p] = acc;
}

extern "C" void kernel_launch(void* const* d_in, const int* in_sizes, int n_in,
                              void* d_out, int out_size, void* d_ws, size_t ws_size,
                              hipStream_t stream) {
    const float* in  = (const float*)d_in[0];
    const float* Wsh = (const float*)d_in[1];
    const float* bsh = (const float*)d_in[2];
    const float* Wp  = (const float*)d_in[15];
    const float* bp  = (const float*)d_in[16];

    // workspace layout (~151.9 MB, proven to fit)
    char* wsb = (char*)d_ws;
    ushort_t* vt   = (ushort_t*)wsb;                          // 1024*1024*64 bf16 = 134,217,728 B
    float* ctab = (float*)(wsb + 134217728);                  // 1024
    float* stab = ctab + 1024;                                // 1024
    float* gT   = stab + 1024;                                // 1024*64*64 f32 = 16 MB
    float* Rfr  = gT + 4194304;                               // 65536
    float* Rfi  = Rfr + 65536;                                // 65536
    ushort_t* T1h = (ushort_t*)(Rfi + 65536);                 // 64*1024
    ushort_t* T1l = T1h + 65536;
    ushort_t* T2h = T1l + 65536;                              // 1024*64
    ushort_t* T2l = T2h + 65536;
    ushort_t* wTh = T2l + 65536;                              // 4*64*64
    ushort_t* wTl = wTh + 16384;
    ushort_t* Bh  = (ushort_t*)gT;                            // alias gT (dead after k_f2)
    ushort_t* Bl  = Bh + 4194304;
    float* fpr = (float*)d_out;                               // alias d_out (dead before k_proj)
    float* fpi = fpr + 524288;

    k_fill_tw<<<4, 256, 0, stream>>>(ctab, stab);
    k_fill_T1<<<256, 256, 0, stream>>>(T1h, T1l);
    k_fill_T2<<<256, 256, 0, stream>>>(T2h, T2l);
    k_fill_wT<<<dim3(16, 4), 256, 0, stream>>>((const float*)d_in[5], (const float*)d_in[8],
                                               (const float*)d_in[11], (const float*)d_in[14], wTh, wTl);
    k_shallow<<<65536, 256, 0, stream>>>(in, Wsh, bsh, vt);
    for (int L = 0; L < 4; ++L) {
        const float* Rr = (const float*)d_in[3 + L * 3];
        const float* Ri = (const float*)d_in[4 + L * 3];
        k_f1<<<1024, 256, 0, stream>>>(vt, T1h, T1l, gT);
        k_f2<<<dim3(8, 16, 4), 256, 0, stream>>>(gT, ctab, stab, fpr, fpi);
        k_mix<<<1024, 64, 0, stream>>>(fpr, fpi, Rr, Ri, Rfr, Rfi);
        k_i1<<<1024, 256, 0, stream>>>(Rfr, Rfi, ctab, stab, Bh, Bl);
        k_i2<<<dim3(8, 1024), 256, 0, stream>>>(vt, Bh, Bl, T2h, T2l,
                                                wTh + L * 4096, wTl + L * 4096);
    }
    k_proj<<<4096, 256, 0, stream>>>(vt, Wp, bp, (float*)d_out);
}